// Round 1
// 866.719 us; speedup vs baseline: 1.2351x; 1.2351x over previous
//
#include <hip/hip_runtime.h>
#include <math.h>

#define BB 8
#define NN 2048
#define KNNK 8
#define SEG 4
#define SEGN (NN/SEG)
#define OBJ 224
#define HWD (OBJ*OBJ)

// MFMA vector types (gfx950 v_mfma_f32_16x16x32_f16: A/B = 8 x f16, C/D = 4 x f32)
typedef _Float16 f16x8 __attribute__((ext_vector_type(8)));
typedef _Float16 f16x4 __attribute__((ext_vector_type(4)));
typedef float    f32x4v __attribute__((ext_vector_type(4)));

// ---------------- workspace layout (float units) ----------------
constexpr size_t RES_SZ  = (size_t)BB*HWD*64;     // 25,690,112 floats
constexpr size_t F_SZ    = (size_t)BB*NN*64;
constexpr size_t F0_SZ   = (size_t)BB*NN*8;
constexpr size_t RES_OFF = 0;
constexpr size_t H1_OFF  = RES_SZ;                // also aliases KNN partials (pre-conv)
constexpr size_t F_OFF   = 2*RES_SZ;
constexpr size_t F0_OFF  = F_OFF + F_SZ;
constexpr size_t BP_OFF  = F0_OFF + F0_SZ;
constexpr size_t GS_OFF  = BP_OFF + 128;
constexpr size_t GM_OFF  = GS_OFF + 64;
constexpr size_t WT1_OFF = GM_OFF + 64;           // 92160 f16 = 46080 floats (frag weights)
constexpr size_t WTF_SZ  = 46080;
constexpr size_t WT2_OFF = WT1_OFF + WTF_SZ;
constexpr size_t INT_OFF = WT2_OFF + WTF_SZ;

// ---------------- K0: conv weights [O][C][3][3] -> split-f16 MFMA B-frags -
// Layout: wf[(((tap*2 + kb)*2 + hl)*64 + o)*40 + kk], kk = k within 32-block,
// kk-stride padded 32->40 f16 so LDS B-frag reads (o-stride 40 f16 = 20 dw)
// are 16B-aligned and ~2-way bank-free. hl=0: hi = (f16)w, hl=1: lo = w - hi.
__global__ void k0_wtf(const float* __restrict__ w, _Float16* __restrict__ wf) {
    int i = blockIdx.x*256 + threadIdx.x;
    if (i >= 92160) return;
    int kk = i % 40;
    int o  = (i/40) & 63;
    int hl = (i/2560) & 1;
    int kb = (i/5120) & 1;
    int tp = i/10240;
    _Float16 v = (_Float16)0.f;
    if (kk < 32) {
        int c = kb*32 + kk;
        float val = w[(size_t)(o*64 + c)*9 + tp];
        _Float16 hi = (_Float16)val;
        v = hl ? (_Float16)(val - (float)hi) : hi;
    }
    wf[i] = v;
}

// ---------------- K1: per-batch grid params — FROZEN (arcp f32, R11) -----
__global__ void k1_params(const float* __restrict__ pc, float* __restrict__ bparam) {
    __shared__ float r0[256], r1[256], r2[256], r3[256];
    __shared__ float sh[4];
    int b = blockIdx.x, t = threadIdx.x;
    const float* p = pc + (size_t)b*NN*3;
    float mnx=1e30f, mxx=-1e30f, mny=1e30f, mxy=-1e30f;
    for (int n=t; n<NN; n+=256) {
        float x=p[3*n], y=p[3*n+1];
        mnx=fminf(mnx,x); mxx=fmaxf(mxx,x); mny=fminf(mny,y); mxy=fmaxf(mxy,y);
    }
    r0[t]=mnx; r1[t]=mxx; r2[t]=mny; r3[t]=mxy;
    __syncthreads();
    for (int s=128; s>0; s>>=1) {
        if (t<s) { r0[t]=fminf(r0[t],r0[t+s]); r1[t]=fmaxf(r1[t],r1[t+s]);
                   r2[t]=fminf(r2[t],r2[t+s]); r3[t]=fmaxf(r3[t],r3[t+s]); }
        __syncthreads();
    }
    if (t==0) {
        float rx = __fsub_rn(r1[0], r0[0]);
        float ry = __fsub_rn(r3[0], r2[0]);
        sh[0]=r0[0]; sh[1]=r2[0];
        float c221 = __fdiv_rn(1.0f, (float)(OBJ-3));
        float grid = __fmul_rn(fmaxf(rx,ry), c221);
        sh[2] = grid;
        sh[3] = __fdiv_rn(1.0f, grid);               // hoisted reciprocal (arcp)
    }
    __syncthreads();
    float minx=sh[0], miny=sh[1], rgrid=sh[3];
    mnx=1e30f; mxx=-1e30f; mny=1e30f; mxy=-1e30f;
    for (int n=t; n<NN; n+=256) {
        float ix = floorf(__fmul_rn(__fsub_rn(p[3*n],   minx), rgrid));
        float iy = floorf(__fmul_rn(__fsub_rn(p[3*n+1], miny), rgrid));
        mnx=fminf(mnx,ix); mxx=fmaxf(mxx,ix); mny=fminf(mny,iy); mxy=fmaxf(mxy,iy);
    }
    __syncthreads();
    r0[t]=mnx; r1[t]=mxx; r2[t]=mny; r3[t]=mxy;
    __syncthreads();
    for (int s=128; s>0; s>>=1) {
        if (t<s) { r0[t]=fminf(r0[t],r0[t+s]); r1[t]=fmaxf(r1[t],r1[t+s]);
                   r2[t]=fminf(r2[t],r2[t+s]); r3[t]=fmaxf(r3[t],r3[t+s]); }
        __syncthreads();
    }
    if (t==0) {
        float cx = floorf((r1[0] + 2.0f + r0[0]) * 0.5f);
        float cy = floorf((r3[0] + 2.0f + r2[0]) * 0.5f);
        bparam[b*8+0]=minx; bparam[b*8+1]=miny; bparam[b*8+2]=sh[3];
        bparam[b*8+3]=112.0f - cx - 1.0f;
        bparam[b*8+4]=112.0f - cy - 1.0f;
    }
}

// ---------------- K2: linear grid indices — FROZEN (arcp) ----------------
__global__ void k2_lin(const float* __restrict__ pc, const float* __restrict__ bparam,
                       int* __restrict__ lin) {
    int i = blockIdx.x*256 + threadIdx.x;
    if (i >= BB*NN) return;
    int b = i / NN;
    float x = pc[(size_t)i*3], y = pc[(size_t)i*3+1];
    float minx=bparam[b*8], miny=bparam[b*8+1], rgrid=bparam[b*8+2];
    float offx=bparam[b*8+3], offy=bparam[b*8+4];
    float ix = floorf(__fmul_rn(__fsub_rn(x, minx), rgrid));
    float iy = floorf(__fmul_rn(__fsub_rn(y, miny), rgrid));
    const float o9x[9] = {-1,-1,-1, 0,0,0, 1,1,1};
    const float o9y[9] = {-1, 0, 1,-1,0,1,-1,0,1};
#pragma unroll
    for (int j=0; j<9; ++j) {
        float dx = ix + o9x[j] + 1.0f + offx;
        float dy = iy + o9y[j] + 1.0f + offy;
        dx += (dx < 0.f ? 1.f : 0.f) - (dx > 223.f ? 1.f : 0.f);
        dy += (dy < 0.f ? 1.f : 0.f) - (dy > 223.f ? 1.f : 0.f);
        lin[(size_t)i*9 + j] = (int)(dx*224.f + dy);
    }
}

// ---------------- K3: f0 = pc @ w_in^T + b_in ----------------
__global__ void k3_f0(const float* __restrict__ pc, const float* __restrict__ w_in,
                      const float* __restrict__ b_in, float* __restrict__ f0) {
    int i = blockIdx.x*256 + threadIdx.x;
    if (i >= BB*NN*8) return;
    int o = i & 7; int bn = i >> 3;
    float x=pc[(size_t)bn*3], y=pc[(size_t)bn*3+1], z=pc[(size_t)bn*3+2];
    f0[i] = x*w_in[o*3] + y*w_in[o*3+1] + z*w_in[o*3+2] + b_in[o];
}

// ---------------- K4: segmented KNN (R12 WIN config) ---------------------
__global__ __launch_bounds__(256) void k4_knn(const float* __restrict__ pc,
                                              float* __restrict__ pd,
                                              int* __restrict__ pi) {
    __shared__ float4 pts[SEGN];
    int b = blockIdx.y, t = threadIdx.x, seg = blockIdx.z;
    const float* p = pc + (size_t)b*NN*3;
    int m0 = seg*SEGN;
    for (int m=t; m<SEGN; m+=256) {
        int mm = m0 + m;
        float x=p[3*mm], y=p[3*mm+1], z=p[3*mm+2];
        float sq = __fadd_rn(__fadd_rn(__fmul_rn(x,x), __fmul_rn(y,y)), __fmul_rn(z,z));
        pts[m] = make_float4(x, y, z, sq);
    }
    __syncthreads();
    int n = blockIdx.x*256 + t;
    float mx = p[3*n], my = p[3*n+1], mz = p[3*n+2];
    float msq = __fadd_rn(__fadd_rn(__fmul_rn(mx,mx), __fmul_rn(my,my)), __fmul_rn(mz,mz));
    float bd[KNNK]; int bi[KNNK];
#pragma unroll
    for (int j=0; j<KNNK; ++j) { bd[j]=1e30f; bi[j]=0; }
#pragma unroll 8
    for (int m=0; m<SEGN; ++m) {
        float4 q = pts[m];
        float dot = __fadd_rn(__fadd_rn(__fmul_rn(mz,q.z), __fmul_rn(my,q.y)),
                              __fmul_rn(mx,q.x));
        float d = __fsub_rn(__fadd_rn(msq, q.w), __fmul_rn(2.0f, dot));
        if (d < bd[KNNK-1]) {
            float v=d; int vi=m0+m;
#pragma unroll
            for (int j=0; j<KNNK; ++j) {
                if (v < bd[j]) { float tv=bd[j]; int ti=bi[j]; bd[j]=v; bi[j]=vi; v=tv; vi=ti; }
            }
        }
    }
    size_t base = (((size_t)b*NN + n)*SEG + seg)*KNNK;
#pragma unroll
    for (int j=0; j<KNNK; ++j) { pd[base+j] = bd[j]; pi[base+j] = bi[j]; }
}

// ---------------- K4b: merge 4 sorted partial top-8 lists ----------------
__global__ void k4b_merge(const float* __restrict__ pd, const int* __restrict__ pi,
                          int* __restrict__ nidx) {
    int i = blockIdx.x*256 + threadIdx.x;
    if (i >= BB*NN) return;
    float d[SEG][KNNK]; int id[SEG][KNNK]; int ptr[SEG];
    size_t base = (size_t)i*SEG*KNNK;
#pragma unroll
    for (int s=0; s<SEG; ++s) {
        ptr[s]=0;
#pragma unroll
        for (int j=0; j<KNNK; ++j) { d[s][j]=pd[base+s*KNNK+j]; id[s][j]=pi[base+s*KNNK+j]; }
    }
#pragma unroll
    for (int j=0; j<KNNK; ++j) {
        int best=0; float bdv=1e30f; int bidx=0x7fffffff;
#pragma unroll
        for (int s=0; s<SEG; ++s) {
            float dv = (ptr[s]<KNNK) ? d[s][ptr[s]] : 1e30f;
            int   iv = (ptr[s]<KNNK) ? id[s][ptr[s]] : 0x7fffffff;
            if (dv < bdv || (dv == bdv && iv < bidx)) { best=s; bdv=dv; bidx=iv; }
        }
        nidx[(size_t)i*KNNK + j] = bidx;
        ptr[best]++;
    }
}

// ---------------- feat builder (shared by K5/K6) ----------------
__device__ __forceinline__ void build_feat(int t, int b, int n0,
        const float* __restrict__ f0, const int* __restrict__ nidx,
        float feat[4][8][16]) {
    int pt = t >> 6, k = (t >> 3) & 7, c = t & 7;
    int n  = n0 + pt;
    int nb = nidx[((size_t)b*NN + n)*8 + k];
    float f0c = f0[((size_t)b*NN + n)*8 + c];
    float fnc = f0[((size_t)b*NN + nb)*8 + c];
    feat[pt][k][c]   = fnc - f0c;
    feat[pt][k][c+8] = f0c;
}

// ---------------- K5: GroupNorm stats pass ----------------
__global__ __launch_bounds__(256) void k5_stats(const float* __restrict__ f0,
        const int* __restrict__ nidx, const float* __restrict__ w_graph,
        float* __restrict__ gsum) {
    __shared__ float wgT[16*64];
    __shared__ float feat[4][8][16];
    __shared__ float part[4][4][2];
    int t = threadIdx.x;
    for (int i=t; i<1024; i+=256) wgT[(i&15)*64 + (i>>4)] = w_graph[i];
    int blk = blockIdx.x;
    int b = blk >> 9, n0 = (blk & 511)*4;
    build_feat(t, b, n0, f0, nidx, feat);
    __syncthreads();
    int pt = t >> 6, o = t & 63;
    float s = 0.f, s2 = 0.f;
#pragma unroll
    for (int k=0; k<8; ++k) {
        float g = 0.f;
#pragma unroll
        for (int c=0; c<16; ++c) g = fmaf(feat[pt][k][c], wgT[c*64+o], g);
        s += g; s2 += g*g;
    }
#pragma unroll
    for (int off=8; off; off>>=1) {
        s  += __shfl_down(s,  off, 16);
        s2 += __shfl_down(s2, off, 16);
    }
    if ((o & 15) == 0) { part[pt][o>>4][0] = s; part[pt][o>>4][1] = s2; }
    __syncthreads();
    if (t < 8) {
        int grp = t >> 1, which = t & 1;
        float v = part[0][grp][which] + part[1][grp][which]
                + part[2][grp][which] + part[3][grp][which];
        atomicAdd(&gsum[(b*4+grp)*2 + which], v);
    }
}

__global__ void k5b_finalize(const float* __restrict__ gsum, float* __restrict__ gmu) {
    int t = threadIdx.x;
    if (t < 32) {
        const float cnt = (float)(NN*KNNK*16);
        float mu = gsum[t*2] / cnt;
        float var = gsum[t*2+1] / cnt - mu*mu;
        gmu[t*2]   = mu;
        gmu[t*2+1] = 1.0f / sqrtf(var + 1e-5f);
    }
}

// ---------------- K6: normalize + leaky + max_k + proj ----------------
__global__ __launch_bounds__(256) void k6_point(const float* __restrict__ f0,
        const int* __restrict__ nidx, const float* __restrict__ w_graph,
        const float* __restrict__ gmu, const float* __restrict__ gn_g,
        const float* __restrict__ gn_b, const float* __restrict__ w_proj,
        const float* __restrict__ b_proj, float* __restrict__ f) {
    __shared__ float wgT[16*64];
    __shared__ float wpT[64*64];
    __shared__ float feat[4][8][16];
    __shared__ float gmax_s[4][64];
    int t = threadIdx.x;
    for (int i=t; i<1024; i+=256) wgT[(i&15)*64 + (i>>4)] = w_graph[i];
    for (int i=t; i<4096; i+=256) wpT[(i&63)*64 + (i>>6)] = w_proj[i];
    int blk = blockIdx.x;
    int b = blk >> 9, n0 = (blk & 511)*4;
    build_feat(t, b, n0, f0, nidx, feat);
    __syncthreads();
    int pt = t >> 6, o = t & 63;
    int grp = o >> 4;
    float mu = gmu[(b*4+grp)*2], rsig = gmu[(b*4+grp)*2+1];
    float ga = gn_g[o], be = gn_b[o];
    float gm = -1e30f;
#pragma unroll
    for (int k=0; k<8; ++k) {
        float g = 0.f;
#pragma unroll
        for (int c=0; c<16; ++c) g = fmaf(feat[pt][k][c], wgT[c*64+o], g);
        float v = (g - mu)*rsig*ga + be;
        v = (v >= 0.f) ? v : 0.2f*v;
        gm = fmaxf(gm, v);
    }
    gmax_s[pt][o] = gm;
    __syncthreads();
    float acc = b_proj[o];
#pragma unroll
    for (int c=0; c<64; ++c) acc = fmaf(gmax_s[pt][c], wpT[c*64+o], acc);
    f[((size_t)b*NN + n0 + pt)*64 + o] = acc;
}

// ---------------- K7: scatter-sum onto NHWC grid (all batches) -----------
__global__ __launch_bounds__(256) void k7_scatter(const float* __restrict__ f,
        const int* __restrict__ lin, float* __restrict__ res) {
    int blk = blockIdx.x, t = threadIdx.x;
    int b = blk >> 9;
    int n = (blk & 511)*4 + (t >> 6);
    int o = t & 63;
    size_t bn = (size_t)b*NN + n;
    float v = f[bn*64 + o];
#pragma unroll
    for (int j=0; j<9; ++j) {
        int cell = lin[bn*9 + j];
        if (cell >= 0 && cell < HWD)
            atomicAdd(&res[((size_t)b*HWD + cell)*64 + o], v);
    }
}

// ======================= split-f16 MFMA conv engine =======================
// Conv as implicit GEMM on matrix cores. fp32 x ~ hi + lo (both f16);
// x*w = hi*wh + lo*wh + hi*wl (+ lo*wl ~ 2^-22, dropped) with fp32 MFMA
// accumulation -> result numerically ~= the fp32 VALU version.
// Tile: 16x16 px/block, 4 waves; wave w owns px [64w,64w+64) (M-frags m=0..3)
// x all 64 outputs (N-tiles n=0..3). Per tap-kblock: 16 ds_read_b128 vs
// 48 MFMA -> matrix-pipe bound. Frag layouts (m89/m91-verified):
//   A: row=lane&15, k=8*(lane>>4)+j   B: col=lane&15, k same
//   D: row=4*(lane>>4)+reg, col=lane&15
// LDS: haloH/haloL [324][72] f16 (stride 72 -> 36dw = 4 mod 32, 2-way free),
// weights [2buf][2kb][2hl][64o][40kk] f16 (o-stride 20dw, 2-way free).
#define LDS_BYTES 134272   // 46656 + 46656 + 40960

__device__ __forceinline__ void conv_mfma_body(
        const float* __restrict__ sp, const _Float16* __restrict__ wf,
        _Float16* haloH, _Float16* haloL, _Float16* wlds,
        int x0, int y0, int t, int wid, int lr, int lg, f32x4v acc[4][4]) {
    // ---- halo stage: 18x18 cells x 64ch fp32 -> hi/lo f16 ----
    for (int i = t; i < 5184; i += 256) {
        int cell = i >> 4, c4 = i & 15;
        int gy = y0 - 1 + cell/18, gx = x0 - 1 + cell%18;
        float4 v = make_float4(0.f,0.f,0.f,0.f);
        if (gy >= 0 && gy < OBJ && gx >= 0 && gx < OBJ)
            v = *(const float4*)(sp + ((size_t)gy*OBJ + gx)*64 + c4*4);
        _Float16 a0=(_Float16)v.x, a1=(_Float16)v.y, a2=(_Float16)v.z, a3=(_Float16)v.w;
        f16x4 hv = {a0, a1, a2, a3};
        f16x4 lv = {(_Float16)(v.x-(float)a0), (_Float16)(v.y-(float)a1),
                    (_Float16)(v.z-(float)a2), (_Float16)(v.w-(float)a3)};
        *(f16x4*)&haloH[cell*72 + c4*4] = hv;
        *(f16x4*)&haloL[cell*72 + c4*4] = lv;
    }
    // ---- stage tap-0 weights ----
    {
        const uint4* s4 = (const uint4*)wf;
        uint4* d4 = (uint4*)wlds;
        for (int i = t; i < 1280; i += 256) d4[i] = s4[i];
    }
    __syncthreads();
    // ---- K-loop: 9 taps x 2 kblocks, weight double-buffer ----
    for (int tp = 0; tp < 9; ++tp) {
        int buf = tp & 1;
        if (tp < 8) {
            const uint4* s4 = (const uint4*)(wf + (size_t)(tp+1)*10240);
            uint4* d4 = (uint4*)(wlds + (buf^1)*10240);
            for (int i = t; i < 1280; i += 256) d4[i] = s4[i];
        }
        int dy = tp/3, dx = tp - 3*(tp/3);
        const _Float16* wb = wlds + buf*10240;
#pragma unroll
        for (int kb = 0; kb < 2; ++kb) {
            f16x8 ah[4], al[4], bh[4], bl[4];
#pragma unroll
            for (int m = 0; m < 4; ++m) {
                int off = ((4*wid + m + dy)*18 + lr + dx)*72 + kb*32 + lg*8;
                ah[m] = *(const f16x8*)&haloH[off];
                al[m] = *(const f16x8*)&haloL[off];
            }
#pragma unroll
            for (int n = 0; n < 4; ++n) {
                int off = (kb*128 + 16*n + lr)*40 + lg*8;   // hl=0 plane
                bh[n] = *(const f16x8*)&wb[off];
                bl[n] = *(const f16x8*)&wb[off + 2560];      // hl=1: +64*40
            }
#pragma unroll
            for (int m = 0; m < 4; ++m)
#pragma unroll
            for (int n = 0; n < 4; ++n) {
                acc[m][n] = __builtin_amdgcn_mfma_f32_16x16x32_f16(ah[m], bh[n], acc[m][n], 0,0,0);
                acc[m][n] = __builtin_amdgcn_mfma_f32_16x16x32_f16(al[m], bh[n], acc[m][n], 0,0,0);
                acc[m][n] = __builtin_amdgcn_mfma_f32_16x16x32_f16(ah[m], bl[n], acc[m][n], 0,0,0);
            }
        }
        __syncthreads();
    }
}

// ---------------- K8: conv3x3 + scale/shift + relu (MFMA) ----------------
__global__ __launch_bounds__(256, 1) void k8m_conv1(
        const float* __restrict__ src, const _Float16* __restrict__ wf,
        const float* __restrict__ g1, const float* __restrict__ b1,
        float* __restrict__ dst) {
    __shared__ __align__(16) char smem[LDS_BYTES];
    _Float16* haloH = (_Float16*)smem;
    _Float16* haloL = (_Float16*)(smem + 46656);
    _Float16* wlds  = (_Float16*)(smem + 93312);
    int x0 = blockIdx.x*16, y0 = blockIdx.y*16, b = blockIdx.z;
    int t = threadIdx.x, wid = t >> 6, lr = t & 15, lg = (t >> 4) & 3;
    f32x4v acc[4][4];
#pragma unroll
    for (int m=0;m<4;++m)
#pragma unroll
    for (int n=0;n<4;++n) acc[m][n] = (f32x4v){0.f,0.f,0.f,0.f};
    conv_mfma_body(src + (size_t)b*HWD*64, wf, haloH, haloL, wlds,
                   x0, y0, t, wid, lr, lg, acc);
    // ---- epilogue: scale/shift + relu, store NHWC ----
    float gv[4], bv[4];
#pragma unroll
    for (int n = 0; n < 4; ++n) { gv[n] = g1[16*n+lr]; bv[n] = b1[16*n+lr]; }
    float* dp = dst + (size_t)b*HWD*64;
#pragma unroll
    for (int m = 0; m < 4; ++m) {
        int py = 4*wid + m;
#pragma unroll
        for (int n = 0; n < 4; ++n)
#pragma unroll
        for (int r = 0; r < 4; ++r) {
            int px = lg*4 + r;
            dp[((size_t)(y0+py)*OBJ + (x0+px))*64 + 16*n + lr] =
                fmaxf(fmaf(acc[m][n][r], gv[n], bv[n]), 0.f);
        }
    }
}

// ---------------- K9: conv3x3 + bn + residual-relu + blkout + img head ---
__global__ __launch_bounds__(256, 1) void k9m_conv2(
        const float* __restrict__ h1, const _Float16* __restrict__ wf,
        const float* __restrict__ g2, const float* __restrict__ b2,
        const float* __restrict__ resi,
        const float* __restrict__ wbk, const float* __restrict__ bbk,
        const float* __restrict__ wim, const float* __restrict__ bim,
        float* __restrict__ outp) {
    __shared__ __align__(16) char smem[LDS_BYTES];
    _Float16* haloH = (_Float16*)smem;
    _Float16* haloL = (_Float16*)(smem + 46656);
    _Float16* wlds  = (_Float16*)(smem + 93312);
    int x0 = blockIdx.x*16, y0 = blockIdx.y*16, b = blockIdx.z;
    int t = threadIdx.x, wid = t >> 6, lr = t & 15, lg = (t >> 4) & 3;
    f32x4v acc[4][4];
#pragma unroll
    for (int m=0;m<4;++m)
#pragma unroll
    for (int n=0;n<4;++n) acc[m][n] = (f32x4v){0.f,0.f,0.f,0.f};
    conv_mfma_body(h1 + (size_t)b*HWD*64, wf, haloH, haloL, wlds,
                   x0, y0, t, wid, lr, lg, acc);
    // ---- phase A: stage wbk B-frags (reuse wlds buf0) + t=relu(bn+res) -> thl
    // (last conv tap read buf0 before the loop's final barrier -> safe)
    _Float16* thlH = haloH;   // [256][72] f16 (hi plane)
    _Float16* thlL = haloL;   // [256][72] f16 (lo plane)
    for (int i = t; i < 4096; i += 256) {
        int o = i >> 6, c = i & 63;
        float val = wbk[i];
        _Float16 hi = (_Float16)val;
        int kb2 = c >> 5, kk = c & 31;
        wlds[(kb2*128 + o)*40 + kk]        = hi;
        wlds[(kb2*128 + 64 + o)*40 + kk]   = (_Float16)(val - (float)hi);
    }
    float g2v[4], b2v[4];
#pragma unroll
    for (int n = 0; n < 4; ++n) { g2v[n] = g2[16*n+lr]; b2v[n] = b2[16*n+lr]; }
    const float* rp = resi + (size_t)b*HWD*64;
#pragma unroll
    for (int m = 0; m < 4; ++m) {
        int py = 4*wid + m;
#pragma unroll
        for (int n = 0; n < 4; ++n)
#pragma unroll
        for (int r = 0; r < 4; ++r) {
            int px = lg*4 + r;
            int pix = 64*wid + 16*m + lg*4 + r;
            float tv = fmaf(acc[m][n][r], g2v[n], b2v[n])
                     + rp[((size_t)(y0+py)*OBJ + (x0+px))*64 + 16*n + lr];
            tv = fmaxf(tv, 0.f);
            _Float16 hi = (_Float16)tv;
            thlH[pix*72 + 16*n + lr] = hi;
            thlL[pix*72 + 16*n + lr] = (_Float16)(tv - (float)hi);
        }
    }
    __syncthreads();
    // ---- phase B: blkout GEMM (64x64) via split-f16 MFMA ----
    f32x4v a2[4][4];
#pragma unroll
    for (int m=0;m<4;++m)
#pragma unroll
    for (int n=0;n<4;++n) a2[m][n] = (f32x4v){0.f,0.f,0.f,0.f};
#pragma unroll
    for (int kb = 0; kb < 2; ++kb) {
        f16x8 ah[4], al[4], bh[4], bl[4];
#pragma unroll
        for (int m = 0; m < 4; ++m) {
            int off = (64*wid + 16*m + lr)*72 + kb*32 + lg*8;
            ah[m] = *(const f16x8*)&thlH[off];
            al[m] = *(const f16x8*)&thlL[off];
        }
#pragma unroll
        for (int n = 0; n < 4; ++n) {
            int off = (kb*128 + 16*n + lr)*40 + lg*8;
            bh[n] = *(const f16x8*)&wlds[off];
            bl[n] = *(const f16x8*)&wlds[off + 2560];
        }
#pragma unroll
        for (int m = 0; m < 4; ++m)
#pragma unroll
        for (int n = 0; n < 4; ++n) {
            a2[m][n] = __builtin_amdgcn_mfma_f32_16x16x32_f16(ah[m], bh[n], a2[m][n], 0,0,0);
            a2[m][n] = __builtin_amdgcn_mfma_f32_16x16x32_f16(al[m], bh[n], a2[m][n], 0,0,0);
            a2[m][n] = __builtin_amdgcn_mfma_f32_16x16x32_f16(ah[m], bl[n], a2[m][n], 0,0,0);
        }
    }
    __syncthreads();          // all thl reads done before ureg overwrites
    // ---- write u = blkout + bbk into LDS [256][67] f32 (stride 67 = 3 mod 32)
    float* ureg = (float*)smem;
    float bkv[4];
#pragma unroll
    for (int n = 0; n < 4; ++n) bkv[n] = bbk[16*n+lr];
#pragma unroll
    for (int m = 0; m < 4; ++m)
#pragma unroll
    for (int n = 0; n < 4; ++n)
#pragma unroll
    for (int r = 0; r < 4; ++r) {
        int pix = 64*wid + 16*m + lg*4 + r;
        ureg[pix*67 + 16*n + lr] = a2[m][n][r] + bkv[n];
    }
    __syncthreads();
    // ---- phase C: img head (3 outputs, VALU) + sigmoid + normalize ----
    {
        const float MEAN[3] = {0.485f, 0.456f, 0.406f};
        const float STDV[3] = {0.229f, 0.224f, 0.225f};
        int pix = t, py = pix >> 4, px = pix & 15;
#pragma unroll
        for (int o3 = 0; o3 < 3; ++o3) {
            float s = bim[o3];
            for (int c = 0; c < 64; ++c)
                s = fmaf(wim[o3*64 + c], ureg[pix*67 + c], s);
            float sig = 1.f/(1.f + expf(-s));
            outp[((size_t)(b*3 + o3))*HWD + (size_t)(y0+py)*OBJ + (x0+px)] =
                (sig - MEAN[o3]) / STDV[o3];
        }
    }
}

// ---------------- launch ----------------
extern "C" void kernel_launch(void* const* d_in, const int* in_sizes, int n_in,
                              void* d_out, int out_size, void* d_ws, size_t ws_size,
                              hipStream_t stream) {
    const float* pc      = (const float*)d_in[0];
    const float* w_in    = (const float*)d_in[1];
    const float* b_in    = (const float*)d_in[2];
    const float* w_graph = (const float*)d_in[3];
    const float* gn_g    = (const float*)d_in[4];
    const float* gn_b    = (const float*)d_in[5];
    const float* w_proj  = (const float*)d_in[6];
    const float* b_proj  = (const float*)d_in[7];
    const float* bb_w1   = (const float*)d_in[8];
    const float* bb_g1   = (const float*)d_in[9];
    const float* bb_b1   = (const float*)d_in[10];
    const float* bb_w2   = (const float*)d_in[11];
    const float* bb_g2   = (const float*)d_in[12];
    const float* bb_b2   = (const float*)d_in[13];
    const float* w_blkout= (const float*)d_in[14];
    const float* b_blkout= (const float*)d_in[15];
    const float* w_img   = (const float*)d_in[16];
    const float* b_img   = (const float*)d_in[17];

    float* ws     = (float*)d_ws;
    float* res    = ws + RES_OFF;
    float* h1     = ws + H1_OFF;
    float* pd     = ws + H1_OFF;
    int*   pi     = (int*)(ws + H1_OFF + (size_t)BB*NN*SEG*KNNK);
    float* f      = ws + F_OFF;
    float* f0     = ws + F0_OFF;
    float* bparam = ws + BP_OFF;
    float* gsum   = ws + GS_OFF;
    float* gmu    = ws + GM_OFF;
    _Float16* wt1f = (_Float16*)(ws + WT1_OFF);
    _Float16* wt2f = (_Float16*)(ws + WT2_OFF);
    int*   lin    = (int*)(ws + INT_OFF);
    int*   nidx   = lin + (size_t)BB*NN*9;
    float* out    = (float*)d_out;

    hipMemsetAsync(res, 0, RES_SZ*sizeof(float), stream);
    hipMemsetAsync(gsum, 0, 64*sizeof(float), stream);

    k0_wtf<<<360, 256, 0, stream>>>(bb_w1, wt1f);
    k0_wtf<<<360, 256, 0, stream>>>(bb_w2, wt2f);
    k1_params<<<BB, 256, 0, stream>>>(pc, bparam);
    k2_lin<<<(BB*NN)/256, 256, 0, stream>>>(pc, bparam, lin);
    k3_f0<<<(BB*NN*8)/256, 256, 0, stream>>>(pc, w_in, b_in, f0);
    k4_knn<<<dim3(NN/256, BB, SEG), 256, 0, stream>>>(pc, pd, pi);
    k4b_merge<<<(BB*NN)/256, 256, 0, stream>>>(pd, pi, nidx);
    k5_stats<<<(BB*NN)/4, 256, 0, stream>>>(f0, nidx, w_graph, gsum);
    k5b_finalize<<<1, 64, 0, stream>>>(gsum, gmu);
    k6_point<<<(BB*NN)/4, 256, 0, stream>>>(f0, nidx, w_graph, gmu, gn_g, gn_b,
                                            w_proj, b_proj, f);
    k7_scatter<<<(BB*NN)/4, 256, 0, stream>>>(f, lin, res);
    k8m_conv1<<<dim3(14, 14, BB), 256, 0, stream>>>(res, wt1f, bb_g1, bb_b1, h1);
    k9m_conv2<<<dim3(14, 14, BB), 256, 0, stream>>>(h1, wt2f, bb_g2, bb_b2, res,
                                                    w_blkout, b_blkout, w_img, b_img, out);
}

// Round 2
// 857.088 us; speedup vs baseline: 1.2490x; 1.0112x over previous
//
#include <hip/hip_runtime.h>
#include <math.h>

#define BB 8
#define NN 2048
#define KNNK 8
#define SEG 4
#define SEGN (NN/SEG)
#define OBJ 224
#define HWD (OBJ*OBJ)

// MFMA vector types (gfx950 v_mfma_f32_16x16x32_f16: A/B = 8 x f16, C/D = 4 x f32)
typedef _Float16 f16x8 __attribute__((ext_vector_type(8)));
typedef _Float16 f16x4 __attribute__((ext_vector_type(4)));
typedef float    f32x4v __attribute__((ext_vector_type(4)));

// ---------------- workspace layout (float units) ----------------
constexpr size_t RES_SZ  = (size_t)BB*HWD*64;     // 25,690,112 floats
constexpr size_t F_SZ    = (size_t)BB*NN*64;
constexpr size_t F0_SZ   = (size_t)BB*NN*8;
constexpr size_t RES_OFF = 0;
constexpr size_t H1_OFF  = RES_SZ;                // also aliases KNN partials (pre-conv)
constexpr size_t F_OFF   = 2*RES_SZ;
constexpr size_t F0_OFF  = F_OFF + F_SZ;
constexpr size_t BP_OFF  = F0_OFF + F0_SZ;
constexpr size_t GS_OFF  = BP_OFF + 128;
constexpr size_t GM_OFF  = GS_OFF + 64;
constexpr size_t WT1_OFF = GM_OFF + 64;           // 92160 f16 = 46080 floats (frag weights)
constexpr size_t WTF_SZ  = 46080;
constexpr size_t WT2_OFF = WT1_OFF + WTF_SZ;
constexpr size_t INT_OFF = WT2_OFF + WTF_SZ;

// ---------------- K0: conv weights [O][C][3][3] -> split-f16 MFMA B-frags -
// Layout: wf[(((tap*2 + kb)*2 + hl)*64 + o)*40 + kk], kk = k within 32-block,
// kk-stride padded 32->40 f16 so LDS B-frag reads (o-stride 40 f16 = 20 dw)
// are 16B-aligned and ~2-way bank-free. hl=0: hi = (f16)w, hl=1: lo = w - hi.
__global__ void k0_wtf(const float* __restrict__ w, _Float16* __restrict__ wf) {
    int i = blockIdx.x*256 + threadIdx.x;
    if (i >= 92160) return;
    int kk = i % 40;
    int o  = (i/40) & 63;
    int hl = (i/2560) & 1;
    int kb = (i/5120) & 1;
    int tp = i/10240;
    _Float16 v = (_Float16)0.f;
    if (kk < 32) {
        int c = kb*32 + kk;
        float val = w[(size_t)(o*64 + c)*9 + tp];
        _Float16 hi = (_Float16)val;
        v = hl ? (_Float16)(val - (float)hi) : hi;
    }
    wf[i] = v;
}

// ---------------- K1: per-batch grid params — FROZEN (arcp f32, R11) -----
__global__ void k1_params(const float* __restrict__ pc, float* __restrict__ bparam) {
    __shared__ float r0[256], r1[256], r2[256], r3[256];
    __shared__ float sh[4];
    int b = blockIdx.x, t = threadIdx.x;
    const float* p = pc + (size_t)b*NN*3;
    float mnx=1e30f, mxx=-1e30f, mny=1e30f, mxy=-1e30f;
    for (int n=t; n<NN; n+=256) {
        float x=p[3*n], y=p[3*n+1];
        mnx=fminf(mnx,x); mxx=fmaxf(mxx,x); mny=fminf(mny,y); mxy=fmaxf(mxy,y);
    }
    r0[t]=mnx; r1[t]=mxx; r2[t]=mny; r3[t]=mxy;
    __syncthreads();
    for (int s=128; s>0; s>>=1) {
        if (t<s) { r0[t]=fminf(r0[t],r0[t+s]); r1[t]=fmaxf(r1[t],r1[t+s]);
                   r2[t]=fminf(r2[t],r2[t+s]); r3[t]=fmaxf(r3[t],r3[t+s]); }
        __syncthreads();
    }
    if (t==0) {
        float rx = __fsub_rn(r1[0], r0[0]);
        float ry = __fsub_rn(r3[0], r2[0]);
        sh[0]=r0[0]; sh[1]=r2[0];
        float c221 = __fdiv_rn(1.0f, (float)(OBJ-3));
        float grid = __fmul_rn(fmaxf(rx,ry), c221);
        sh[2] = grid;
        sh[3] = __fdiv_rn(1.0f, grid);               // hoisted reciprocal (arcp)
    }
    __syncthreads();
    float minx=sh[0], miny=sh[1], rgrid=sh[3];
    mnx=1e30f; mxx=-1e30f; mny=1e30f; mxy=-1e30f;
    for (int n=t; n<NN; n+=256) {
        float ix = floorf(__fmul_rn(__fsub_rn(p[3*n],   minx), rgrid));
        float iy = floorf(__fmul_rn(__fsub_rn(p[3*n+1], miny), rgrid));
        mnx=fminf(mnx,ix); mxx=fmaxf(mxx,ix); mny=fminf(mny,iy); mxy=fmaxf(mxy,iy);
    }
    __syncthreads();
    r0[t]=mnx; r1[t]=mxx; r2[t]=mny; r3[t]=mxy;
    __syncthreads();
    for (int s=128; s>0; s>>=1) {
        if (t<s) { r0[t]=fminf(r0[t],r0[t+s]); r1[t]=fmaxf(r1[t],r1[t+s]);
                   r2[t]=fminf(r2[t],r2[t+s]); r3[t]=fmaxf(r3[t],r3[t+s]); }
        __syncthreads();
    }
    if (t==0) {
        float cx = floorf((r1[0] + 2.0f + r0[0]) * 0.5f);
        float cy = floorf((r3[0] + 2.0f + r2[0]) * 0.5f);
        bparam[b*8+0]=minx; bparam[b*8+1]=miny; bparam[b*8+2]=sh[3];
        bparam[b*8+3]=112.0f - cx - 1.0f;
        bparam[b*8+4]=112.0f - cy - 1.0f;
    }
}

// ---------------- K2: linear grid indices — FROZEN (arcp) ----------------
__global__ void k2_lin(const float* __restrict__ pc, const float* __restrict__ bparam,
                       int* __restrict__ lin) {
    int i = blockIdx.x*256 + threadIdx.x;
    if (i >= BB*NN) return;
    int b = i / NN;
    float x = pc[(size_t)i*3], y = pc[(size_t)i*3+1];
    float minx=bparam[b*8], miny=bparam[b*8+1], rgrid=bparam[b*8+2];
    float offx=bparam[b*8+3], offy=bparam[b*8+4];
    float ix = floorf(__fmul_rn(__fsub_rn(x, minx), rgrid));
    float iy = floorf(__fmul_rn(__fsub_rn(y, miny), rgrid));
    const float o9x[9] = {-1,-1,-1, 0,0,0, 1,1,1};
    const float o9y[9] = {-1, 0, 1,-1,0,1,-1,0,1};
#pragma unroll
    for (int j=0; j<9; ++j) {
        float dx = ix + o9x[j] + 1.0f + offx;
        float dy = iy + o9y[j] + 1.0f + offy;
        dx += (dx < 0.f ? 1.f : 0.f) - (dx > 223.f ? 1.f : 0.f);
        dy += (dy < 0.f ? 1.f : 0.f) - (dy > 223.f ? 1.f : 0.f);
        lin[(size_t)i*9 + j] = (int)(dx*224.f + dy);
    }
}

// ---------------- K3: f0 = pc @ w_in^T + b_in ----------------
__global__ void k3_f0(const float* __restrict__ pc, const float* __restrict__ w_in,
                      const float* __restrict__ b_in, float* __restrict__ f0) {
    int i = blockIdx.x*256 + threadIdx.x;
    if (i >= BB*NN*8) return;
    int o = i & 7; int bn = i >> 3;
    float x=pc[(size_t)bn*3], y=pc[(size_t)bn*3+1], z=pc[(size_t)bn*3+2];
    f0[i] = x*w_in[o*3] + y*w_in[o*3+1] + z*w_in[o*3+2] + b_in[o];
}

// ---------------- K4: segmented KNN (R12 WIN config) ---------------------
__global__ __launch_bounds__(256) void k4_knn(const float* __restrict__ pc,
                                              float* __restrict__ pd,
                                              int* __restrict__ pi) {
    __shared__ float4 pts[SEGN];
    int b = blockIdx.y, t = threadIdx.x, seg = blockIdx.z;
    const float* p = pc + (size_t)b*NN*3;
    int m0 = seg*SEGN;
    for (int m=t; m<SEGN; m+=256) {
        int mm = m0 + m;
        float x=p[3*mm], y=p[3*mm+1], z=p[3*mm+2];
        float sq = __fadd_rn(__fadd_rn(__fmul_rn(x,x), __fmul_rn(y,y)), __fmul_rn(z,z));
        pts[m] = make_float4(x, y, z, sq);
    }
    __syncthreads();
    int n = blockIdx.x*256 + t;
    float mx = p[3*n], my = p[3*n+1], mz = p[3*n+2];
    float msq = __fadd_rn(__fadd_rn(__fmul_rn(mx,mx), __fmul_rn(my,my)), __fmul_rn(mz,mz));
    float bd[KNNK]; int bi[KNNK];
#pragma unroll
    for (int j=0; j<KNNK; ++j) { bd[j]=1e30f; bi[j]=0; }
#pragma unroll 8
    for (int m=0; m<SEGN; ++m) {
        float4 q = pts[m];
        float dot = __fadd_rn(__fadd_rn(__fmul_rn(mz,q.z), __fmul_rn(my,q.y)),
                              __fmul_rn(mx,q.x));
        float d = __fsub_rn(__fadd_rn(msq, q.w), __fmul_rn(2.0f, dot));
        if (d < bd[KNNK-1]) {
            float v=d; int vi=m0+m;
#pragma unroll
            for (int j=0; j<KNNK; ++j) {
                if (v < bd[j]) { float tv=bd[j]; int ti=bi[j]; bd[j]=v; bi[j]=vi; v=tv; vi=ti; }
            }
        }
    }
    size_t base = (((size_t)b*NN + n)*SEG + seg)*KNNK;
#pragma unroll
    for (int j=0; j<KNNK; ++j) { pd[base+j] = bd[j]; pi[base+j] = bi[j]; }
}

// ---------------- K4b: merge 4 sorted partial top-8 lists ----------------
__global__ void k4b_merge(const float* __restrict__ pd, const int* __restrict__ pi,
                          int* __restrict__ nidx) {
    int i = blockIdx.x*256 + threadIdx.x;
    if (i >= BB*NN) return;
    float d[SEG][KNNK]; int id[SEG][KNNK]; int ptr[SEG];
    size_t base = (size_t)i*SEG*KNNK;
#pragma unroll
    for (int s=0; s<SEG; ++s) {
        ptr[s]=0;
#pragma unroll
        for (int j=0; j<KNNK; ++j) { d[s][j]=pd[base+s*KNNK+j]; id[s][j]=pi[base+s*KNNK+j]; }
    }
#pragma unroll
    for (int j=0; j<KNNK; ++j) {
        int best=0; float bdv=1e30f; int bidx=0x7fffffff;
#pragma unroll
        for (int s=0; s<SEG; ++s) {
            float dv = (ptr[s]<KNNK) ? d[s][ptr[s]] : 1e30f;
            int   iv = (ptr[s]<KNNK) ? id[s][ptr[s]] : 0x7fffffff;
            if (dv < bdv || (dv == bdv && iv < bidx)) { best=s; bdv=dv; bidx=iv; }
        }
        nidx[(size_t)i*KNNK + j] = bidx;
        ptr[best]++;
    }
}

// ---------------- feat builder (shared by K5/K6) ----------------
__device__ __forceinline__ void build_feat(int t, int b, int n0,
        const float* __restrict__ f0, const int* __restrict__ nidx,
        float feat[4][8][16]) {
    int pt = t >> 6, k = (t >> 3) & 7, c = t & 7;
    int n  = n0 + pt;
    int nb = nidx[((size_t)b*NN + n)*8 + k];
    float f0c = f0[((size_t)b*NN + n)*8 + c];
    float fnc = f0[((size_t)b*NN + nb)*8 + c];
    feat[pt][k][c]   = fnc - f0c;
    feat[pt][k][c+8] = f0c;
}

// ---------------- K5: GroupNorm stats pass ----------------
__global__ __launch_bounds__(256) void k5_stats(const float* __restrict__ f0,
        const int* __restrict__ nidx, const float* __restrict__ w_graph,
        float* __restrict__ gsum) {
    __shared__ float wgT[16*64];
    __shared__ float feat[4][8][16];
    __shared__ float part[4][4][2];
    int t = threadIdx.x;
    for (int i=t; i<1024; i+=256) wgT[(i&15)*64 + (i>>4)] = w_graph[i];
    int blk = blockIdx.x;
    int b = blk >> 9, n0 = (blk & 511)*4;
    build_feat(t, b, n0, f0, nidx, feat);
    __syncthreads();
    int pt = t >> 6, o = t & 63;
    float s = 0.f, s2 = 0.f;
#pragma unroll
    for (int k=0; k<8; ++k) {
        float g = 0.f;
#pragma unroll
        for (int c=0; c<16; ++c) g = fmaf(feat[pt][k][c], wgT[c*64+o], g);
        s += g; s2 += g*g;
    }
#pragma unroll
    for (int off=8; off; off>>=1) {
        s  += __shfl_down(s,  off, 16);
        s2 += __shfl_down(s2, off, 16);
    }
    if ((o & 15) == 0) { part[pt][o>>4][0] = s; part[pt][o>>4][1] = s2; }
    __syncthreads();
    if (t < 8) {
        int grp = t >> 1, which = t & 1;
        float v = part[0][grp][which] + part[1][grp][which]
                + part[2][grp][which] + part[3][grp][which];
        atomicAdd(&gsum[(b*4+grp)*2 + which], v);
    }
}

__global__ void k5b_finalize(const float* __restrict__ gsum, float* __restrict__ gmu) {
    int t = threadIdx.x;
    if (t < 32) {
        const float cnt = (float)(NN*KNNK*16);
        float mu = gsum[t*2] / cnt;
        float var = gsum[t*2+1] / cnt - mu*mu;
        gmu[t*2]   = mu;
        gmu[t*2+1] = 1.0f / sqrtf(var + 1e-5f);
    }
}

// ---------------- K6: normalize + leaky + max_k + proj ----------------
__global__ __launch_bounds__(256) void k6_point(const float* __restrict__ f0,
        const int* __restrict__ nidx, const float* __restrict__ w_graph,
        const float* __restrict__ gmu, const float* __restrict__ gn_g,
        const float* __restrict__ gn_b, const float* __restrict__ w_proj,
        const float* __restrict__ b_proj, float* __restrict__ f) {
    __shared__ float wgT[16*64];
    __shared__ float wpT[64*64];
    __shared__ float feat[4][8][16];
    __shared__ float gmax_s[4][64];
    int t = threadIdx.x;
    for (int i=t; i<1024; i+=256) wgT[(i&15)*64 + (i>>4)] = w_graph[i];
    for (int i=t; i<4096; i+=256) wpT[(i&63)*64 + (i>>6)] = w_proj[i];
    int blk = blockIdx.x;
    int b = blk >> 9, n0 = (blk & 511)*4;
    build_feat(t, b, n0, f0, nidx, feat);
    __syncthreads();
    int pt = t >> 6, o = t & 63;
    int grp = o >> 4;
    float mu = gmu[(b*4+grp)*2], rsig = gmu[(b*4+grp)*2+1];
    float ga = gn_g[o], be = gn_b[o];
    float gm = -1e30f;
#pragma unroll
    for (int k=0; k<8; ++k) {
        float g = 0.f;
#pragma unroll
        for (int c=0; c<16; ++c) g = fmaf(feat[pt][k][c], wgT[c*64+o], g);
        float v = (g - mu)*rsig*ga + be;
        v = (v >= 0.f) ? v : 0.2f*v;
        gm = fmaxf(gm, v);
    }
    gmax_s[pt][o] = gm;
    __syncthreads();
    float acc = b_proj[o];
#pragma unroll
    for (int c=0; c<64; ++c) acc = fmaf(gmax_s[pt][c], wpT[c*64+o], acc);
    f[((size_t)b*NN + n0 + pt)*64 + o] = acc;
}

// ---------------- K7: scatter-sum onto NHWC grid (all batches) -----------
__global__ __launch_bounds__(256) void k7_scatter(const float* __restrict__ f,
        const int* __restrict__ lin, float* __restrict__ res) {
    int blk = blockIdx.x, t = threadIdx.x;
    int b = blk >> 9;
    int n = (blk & 511)*4 + (t >> 6);
    int o = t & 63;
    size_t bn = (size_t)b*NN + n;
    float v = f[bn*64 + o];
#pragma unroll
    for (int j=0; j<9; ++j) {
        int cell = lin[bn*9 + j];
        if (cell >= 0 && cell < HWD)
            atomicAdd(&res[((size_t)b*HWD + cell)*64 + o], v);
    }
}

// ======================= split-f16 MFMA conv engine =======================
// R1 -> R2: 16x16 tile @134 KB LDS gave 1 block/CU (Occupancy 10.4%,
// MfmaUtil 15.7%, ~70% stall). Now 16x8 tile: halo 10x18 hi/lo (51.8 KB) +
// single-buffered weights (20.5 KB) = 72.3 KB -> 2 blocks/CU. Weight
// prefetch is T14 async-split: issue next-tap global loads at tap start
// (hide under 48 MFMAs), ds_write after the tap's barrier.
// Frag layouts (m89/m91-verified, identical to the R1 kernel that passed):
//   A: row=lane&15 (x pos), B: col=lane&15 (out ch), D: row=lg*4+reg (x),
//   col=lane&15 (ch); identical lane->k maps on A/B so k-perm cancels.
// LDS map (bytes): haloH @0 [180][72]f16 (25920), haloL @25920,
//                  wlds @51840 (20480) -> 72320 total.
#define LDS2_BYTES 72320

__device__ __forceinline__ void conv_mfma_body(
        const float* __restrict__ sp, const _Float16* __restrict__ wf,
        _Float16* haloH, _Float16* haloL, _Float16* wlds,
        int x0, int y0, int t, int wid, int lr, int lg, f32x4v acc[2][4]) {
    // ---- halo stage: 10x18 cells x 64ch fp32 -> hi/lo f16 ----
    for (int i = t; i < 2880; i += 256) {
        int cell = i >> 4, c4 = i & 15;
        int gy = y0 - 1 + cell/18, gx = x0 - 1 + cell%18;
        float4 v = make_float4(0.f,0.f,0.f,0.f);
        if (gy >= 0 && gy < OBJ && gx >= 0 && gx < OBJ)
            v = *(const float4*)(sp + ((size_t)gy*OBJ + gx)*64 + c4*4);
        _Float16 a0=(_Float16)v.x, a1=(_Float16)v.y, a2=(_Float16)v.z, a3=(_Float16)v.w;
        f16x4 hv = {a0, a1, a2, a3};
        f16x4 lv = {(_Float16)(v.x-(float)a0), (_Float16)(v.y-(float)a1),
                    (_Float16)(v.z-(float)a2), (_Float16)(v.w-(float)a3)};
        *(f16x4*)&haloH[cell*72 + c4*4] = hv;
        *(f16x4*)&haloL[cell*72 + c4*4] = lv;
    }
    // ---- tap-0 weights: global -> regs -> LDS (1280 uint4 / 256 thr = 5) --
    uint4 wreg[5];
    {
        const uint4* s4 = (const uint4*)wf;
#pragma unroll
        for (int j=0; j<5; ++j) wreg[j] = s4[j*256 + t];
        uint4* d4 = (uint4*)wlds;
#pragma unroll
        for (int j=0; j<5; ++j) d4[j*256 + t] = wreg[j];
    }
    __syncthreads();
    // ---- K-loop: 9 taps x 2 kblocks, single weight buffer + async prefetch
    for (int tp = 0; tp < 9; ++tp) {
        if (tp < 8) {             // issue next tap's loads early (T14 split)
            const uint4* s4 = (const uint4*)(wf + (size_t)(tp+1)*10240);
#pragma unroll
            for (int j=0; j<5; ++j) wreg[j] = s4[j*256 + t];
        }
        int dy = tp/3, dx = tp - 3*(tp/3);
#pragma unroll
        for (int kb = 0; kb < 2; ++kb) {
            f16x8 ah[2], al[2], bh[4], bl[4];
#pragma unroll
            for (int m = 0; m < 2; ++m) {
                int off = ((2*wid + m + dy)*18 + lr + dx)*72 + kb*32 + lg*8;
                ah[m] = *(const f16x8*)&haloH[off];
                al[m] = *(const f16x8*)&haloL[off];
            }
#pragma unroll
            for (int n = 0; n < 4; ++n) {
                int off = (kb*128 + 16*n + lr)*40 + lg*8;   // hl=0 plane
                bh[n] = *(const f16x8*)&wlds[off];
                bl[n] = *(const f16x8*)&wlds[off + 2560];    // hl=1: +64*40
            }
#pragma unroll
            for (int m = 0; m < 2; ++m)
#pragma unroll
            for (int n = 0; n < 4; ++n) {
                acc[m][n] = __builtin_amdgcn_mfma_f32_16x16x32_f16(ah[m], bh[n], acc[m][n], 0,0,0);
                acc[m][n] = __builtin_amdgcn_mfma_f32_16x16x32_f16(al[m], bh[n], acc[m][n], 0,0,0);
                acc[m][n] = __builtin_amdgcn_mfma_f32_16x16x32_f16(ah[m], bl[n], acc[m][n], 0,0,0);
            }
        }
        __syncthreads();                      // all waves done reading wlds
        if (tp < 8) {
            uint4* d4 = (uint4*)wlds;
#pragma unroll
            for (int j=0; j<5; ++j) d4[j*256 + t] = wreg[j];
            __syncthreads();                  // tap tp+1 weights visible
        }
    }
}

// ---------------- K8: conv3x3 + scale/shift + relu (MFMA, 16x8 tile) -----
__global__ __launch_bounds__(256, 2) void k8m_conv1(
        const float* __restrict__ src, const _Float16* __restrict__ wf,
        const float* __restrict__ g1, const float* __restrict__ b1,
        float* __restrict__ dst) {
    __shared__ __align__(16) char smem[LDS2_BYTES];
    _Float16* haloH = (_Float16*)smem;
    _Float16* haloL = (_Float16*)(smem + 25920);
    _Float16* wlds  = (_Float16*)(smem + 51840);
    int x0 = blockIdx.x*16, y0 = blockIdx.y*8, b = blockIdx.z;
    int t = threadIdx.x, wid = t >> 6, lr = t & 15, lg = (t >> 4) & 3;
    f32x4v acc[2][4];
#pragma unroll
    for (int m=0;m<2;++m)
#pragma unroll
    for (int n=0;n<4;++n) acc[m][n] = (f32x4v){0.f,0.f,0.f,0.f};
    conv_mfma_body(src + (size_t)b*HWD*64, wf, haloH, haloL, wlds,
                   x0, y0, t, wid, lr, lg, acc);
    // ---- epilogue: scale/shift + relu, store NHWC ----
    float gv[4], bv[4];
#pragma unroll
    for (int n = 0; n < 4; ++n) { gv[n] = g1[16*n+lr]; bv[n] = b1[16*n+lr]; }
    float* dp = dst + (size_t)b*HWD*64;
#pragma unroll
    for (int m = 0; m < 2; ++m) {
        int py = 2*wid + m;
#pragma unroll
        for (int n = 0; n < 4; ++n)
#pragma unroll
        for (int r = 0; r < 4; ++r) {
            int px = lg*4 + r;
            dp[((size_t)(y0+py)*OBJ + (x0+px))*64 + 16*n + lr] =
                fmaxf(fmaf(acc[m][n][r], gv[n], bv[n]), 0.f);
        }
    }
}

// ---------------- K9: conv3x3 + bn + residual-relu + blkout + img head ---
__global__ __launch_bounds__(256, 2) void k9m_conv2(
        const float* __restrict__ h1, const _Float16* __restrict__ wf,
        const float* __restrict__ g2, const float* __restrict__ b2,
        const float* __restrict__ resi,
        const float* __restrict__ wbk, const float* __restrict__ bbk,
        const float* __restrict__ wim, const float* __restrict__ bim,
        float* __restrict__ outp) {
    __shared__ __align__(16) char smem[LDS2_BYTES];
    _Float16* haloH = (_Float16*)smem;
    _Float16* haloL = (_Float16*)(smem + 25920);
    _Float16* wlds  = (_Float16*)(smem + 51840);
    int x0 = blockIdx.x*16, y0 = blockIdx.y*8, b = blockIdx.z;
    int t = threadIdx.x, wid = t >> 6, lr = t & 15, lg = (t >> 4) & 3;
    f32x4v acc[2][4];
#pragma unroll
    for (int m=0;m<2;++m)
#pragma unroll
    for (int n=0;n<4;++n) acc[m][n] = (f32x4v){0.f,0.f,0.f,0.f};
    conv_mfma_body(h1 + (size_t)b*HWD*64, wf, haloH, haloL, wlds,
                   x0, y0, t, wid, lr, lg, acc);
    // conv loop ended with a barrier -> halo area & wlds reusable.
    // ---- phase A: stage res tile (f32, vectorized) + wbk B-frags ----
    float* reslds = (float*)smem;            // [128][68] f32 = 34816 B
    {
        const float* rp = resi + (size_t)b*HWD*64;
        for (int i = t; i < 2048; i += 256) {
            int pix = i >> 4, c4 = i & 15;
            int gy = y0 + (pix >> 4), gx = x0 + (pix & 15);
            float4 v = *(const float4*)(rp + ((size_t)gy*OBJ + gx)*64 + c4*4);
            *(float4*)&reslds[pix*68 + c4*4] = v;
        }
        for (int i = t; i < 4096; i += 256) {
            int o = i >> 6, c = i & 63;
            float val = wbk[i];
            _Float16 hi = (_Float16)val;
            int kb2 = c >> 5, kk = c & 31;
            wlds[(kb2*128 + o)*40 + kk]      = hi;
            wlds[(kb2*128 + 64 + o)*40 + kk] = (_Float16)(val - (float)hi);
        }
    }
    float g2v[4], b2v[4];
#pragma unroll
    for (int n = 0; n < 4; ++n) { g2v[n] = g2[16*n+lr]; b2v[n] = b2[16*n+lr]; }
    __syncthreads();
    // ---- residual + relu into acc regs (reads reslds) ----
#pragma unroll
    for (int m = 0; m < 2; ++m)
#pragma unroll
    for (int n = 0; n < 4; ++n)
#pragma unroll
    for (int r = 0; r < 4; ++r) {
        int pix = 32*wid + 16*m + lg*4 + r;
        float tv = fmaf(acc[m][n][r], g2v[n], b2v[n]) + reslds[pix*68 + 16*n + lr];
        acc[m][n][r] = fmaxf(tv, 0.f);
    }
    __syncthreads();
    // ---- write t as hi/lo planes for blkout A-frags ----
    _Float16* thlH = (_Float16*)smem;                 // [128][72] f16 = 18432 B
    _Float16* thlL = (_Float16*)(smem + 18432);
#pragma unroll
    for (int m = 0; m < 2; ++m)
#pragma unroll
    for (int n = 0; n < 4; ++n)
#pragma unroll
    for (int r = 0; r < 4; ++r) {
        int pix = 32*wid + 16*m + lg*4 + r;
        float tv = acc[m][n][r];
        _Float16 hi = (_Float16)tv;
        thlH[pix*72 + 16*n + lr] = hi;
        thlL[pix*72 + 16*n + lr] = (_Float16)(tv - (float)hi);
    }
    __syncthreads();
    // ---- phase B: blkout GEMM (128x64, K=64) via split-f16 MFMA ----
    f32x4v a2[2][4];
#pragma unroll
    for (int m=0;m<2;++m)
#pragma unroll
    for (int n=0;n<4;++n) a2[m][n] = (f32x4v){0.f,0.f,0.f,0.f};
#pragma unroll
    for (int kb = 0; kb < 2; ++kb) {
        f16x8 ah[2], al[2], bh[4], bl[4];
#pragma unroll
        for (int m = 0; m < 2; ++m) {
            int off = (32*wid + 16*m + lr)*72 + kb*32 + lg*8;
            ah[m] = *(const f16x8*)&thlH[off];
            al[m] = *(const f16x8*)&thlL[off];
        }
#pragma unroll
        for (int n = 0; n < 4; ++n) {
            int off = (kb*128 + 16*n + lr)*40 + lg*8;
            bh[n] = *(const f16x8*)&wlds[off];
            bl[n] = *(const f16x8*)&wlds[off + 2560];
        }
#pragma unroll
        for (int m = 0; m < 2; ++m)
#pragma unroll
        for (int n = 0; n < 4; ++n) {
            a2[m][n] = __builtin_amdgcn_mfma_f32_16x16x32_f16(ah[m], bh[n], a2[m][n], 0,0,0);
            a2[m][n] = __builtin_amdgcn_mfma_f32_16x16x32_f16(al[m], bh[n], a2[m][n], 0,0,0);
            a2[m][n] = __builtin_amdgcn_mfma_f32_16x16x32_f16(ah[m], bl[n], a2[m][n], 0,0,0);
        }
    }
    __syncthreads();          // all thl reads done before ureg overwrites
    // ---- write u = blkout + bbk into LDS [128][68] f32 ----
    float* ureg = (float*)smem;
    float bkv[4];
#pragma unroll
    for (int n = 0; n < 4; ++n) bkv[n] = bbk[16*n+lr];
#pragma unroll
    for (int m = 0; m < 2; ++m)
#pragma unroll
    for (int n = 0; n < 4; ++n)
#pragma unroll
    for (int r = 0; r < 4; ++r) {
        int pix = 32*wid + 16*m + lg*4 + r;
        ureg[pix*68 + 16*n + lr] = a2[m][n][r] + bkv[n];
    }
    __syncthreads();
    // ---- phase C: img head (3 outputs, VALU) + sigmoid + normalize ----
    if (t < 128) {
        const float MEAN[3] = {0.485f, 0.456f, 0.406f};
        const float STDV[3] = {0.229f, 0.224f, 0.225f};
        int pix = t, py = pix >> 4, px = pix & 15;
#pragma unroll
        for (int o3 = 0; o3 < 3; ++o3) {
            float s = bim[o3];
            for (int c = 0; c < 64; ++c)
                s = fmaf(wim[o3*64 + c], ureg[pix*68 + c], s);
            float sig = 1.f/(1.f + expf(-s));
            outp[((size_t)(b*3 + o3))*HWD + (size_t)(y0+py)*OBJ + (x0+px)] =
                (sig - MEAN[o3]) / STDV[o3];
        }
    }
}

// ---------------- launch ----------------
extern "C" void kernel_launch(void* const* d_in, const int* in_sizes, int n_in,
                              void* d_out, int out_size, void* d_ws, size_t ws_size,
                              hipStream_t stream) {
    const float* pc      = (const float*)d_in[0];
    const float* w_in    = (const float*)d_in[1];
    const float* b_in    = (const float*)d_in[2];
    const float* w_graph = (const float*)d_in[3];
    const float* gn_g    = (const float*)d_in[4];
    const float* gn_b    = (const float*)d_in[5];
    const float* w_proj  = (const float*)d_in[6];
    const float* b_proj  = (const float*)d_in[7];
    const float* bb_w1   = (const float*)d_in[8];
    const float* bb_g1   = (const float*)d_in[9];
    const float* bb_b1   = (const float*)d_in[10];
    const float* bb_w2   = (const float*)d_in[11];
    const float* bb_g2   = (const float*)d_in[12];
    const float* bb_b2   = (const float*)d_in[13];
    const float* w_blkout= (const float*)d_in[14];
    const float* b_blkout= (const float*)d_in[15];
    const float* w_img   = (const float*)d_in[16];
    const float* b_img   = (const float*)d_in[17];

    float* ws     = (float*)d_ws;
    float* res    = ws + RES_OFF;
    float* h1     = ws + H1_OFF;
    float* pd     = ws + H1_OFF;
    int*   pi     = (int*)(ws + H1_OFF + (size_t)BB*NN*SEG*KNNK);
    float* f      = ws + F_OFF;
    float* f0     = ws + F0_OFF;
    float* bparam = ws + BP_OFF;
    float* gsum   = ws + GS_OFF;
    float* gmu    = ws + GM_OFF;
    _Float16* wt1f = (_Float16*)(ws + WT1_OFF);
    _Float16* wt2f = (_Float16*)(ws + WT2_OFF);
    int*   lin    = (int*)(ws + INT_OFF);
    int*   nidx   = lin + (size_t)BB*NN*9;
    float* out    = (float*)d_out;

    hipMemsetAsync(res, 0, RES_SZ*sizeof(float), stream);
    hipMemsetAsync(gsum, 0, 64*sizeof(float), stream);

    k0_wtf<<<360, 256, 0, stream>>>(bb_w1, wt1f);
    k0_wtf<<<360, 256, 0, stream>>>(bb_w2, wt2f);
    k1_params<<<BB, 256, 0, stream>>>(pc, bparam);
    k2_lin<<<(BB*NN)/256, 256, 0, stream>>>(pc, bparam, lin);
    k3_f0<<<(BB*NN*8)/256, 256, 0, stream>>>(pc, w_in, b_in, f0);
    k4_knn<<<dim3(NN/256, BB, SEG), 256, 0, stream>>>(pc, pd, pi);
    k4b_merge<<<(BB*NN)/256, 256, 0, stream>>>(pd, pi, nidx);
    k5_stats<<<(BB*NN)/4, 256, 0, stream>>>(f0, nidx, w_graph, gsum);
    k5b_finalize<<<1, 64, 0, stream>>>(gsum, gmu);
    k6_point<<<(BB*NN)/4, 256, 0, stream>>>(f0, nidx, w_graph, gmu, gn_g, gn_b,
                                            w_proj, b_proj, f);
    k7_scatter<<<(BB*NN)/4, 256, 0, stream>>>(f, lin, res);
    k8m_conv1<<<dim3(14, 28, BB), 256, 0, stream>>>(res, wt1f, bb_g1, bb_b1, h1);
    k9m_conv2<<<dim3(14, 28, BB), 256, 0, stream>>>(h1, wt2f, bb_g2, bb_b2, res,
                                                    w_blkout, b_blkout, w_img, b_img, out);
}

// Round 3
// 837.686 us; speedup vs baseline: 1.2779x; 1.0232x over previous
//
#include <hip/hip_runtime.h>
#include <math.h>

#define BB 8
#define NN 2048
#define KNNK 8
#define SEG 4
#define SEGN (NN/SEG)
#define OBJ 224
#define HWD (OBJ*OBJ)

// MFMA vector types (gfx950 v_mfma_f32_16x16x32_f16: A/B = 8 x f16, C/D = 4 x f32)
typedef _Float16 f16x8 __attribute__((ext_vector_type(8)));
typedef _Float16 f16x4 __attribute__((ext_vector_type(4)));
typedef float    f32x4v __attribute__((ext_vector_type(4)));

// ---------------- workspace layout (float units) ----------------
constexpr size_t RES_SZ  = (size_t)BB*HWD*64;     // 25,690,112 floats
constexpr size_t F_SZ    = (size_t)BB*NN*64;
constexpr size_t F0_SZ   = (size_t)BB*NN*8;
constexpr size_t RES_OFF = 0;
constexpr size_t H1_OFF  = RES_SZ;                // also aliases KNN partials (pre-conv)
constexpr size_t F_OFF   = 2*RES_SZ;
constexpr size_t F0_OFF  = F_OFF + F_SZ;
constexpr size_t BP_OFF  = F0_OFF + F0_SZ;
constexpr size_t GS_OFF  = BP_OFF + 128;
constexpr size_t GM_OFF  = GS_OFF + 64;
constexpr size_t WT1_OFF = GM_OFF + 64;           // 92160 f16 = 46080 floats (frag weights)
constexpr size_t WTF_SZ  = 46080;
constexpr size_t WT2_OFF = WT1_OFF + WTF_SZ;
constexpr size_t INT_OFF = WT2_OFF + WTF_SZ;

// ---------------- K0: conv weights [O][C][3][3] -> split-f16 MFMA B-frags -
// Layout: wf[(((tap*2 + kb)*2 + hl)*64 + o)*40 + kk], kk = k within 32-block,
// kk-stride padded 32->40 f16 so LDS B-frag reads (o-stride 40 f16 = 20 dw)
// are 16B-aligned and ~2-way bank-free. hl=0: hi = (f16)w, hl=1: lo = w - hi.
__global__ void k0_wtf(const float* __restrict__ w, _Float16* __restrict__ wf) {
    int i = blockIdx.x*256 + threadIdx.x;
    if (i >= 92160) return;
    int kk = i % 40;
    int o  = (i/40) & 63;
    int hl = (i/2560) & 1;
    int kb = (i/5120) & 1;
    int tp = i/10240;
    _Float16 v = (_Float16)0.f;
    if (kk < 32) {
        int c = kb*32 + kk;
        float val = w[(size_t)(o*64 + c)*9 + tp];
        _Float16 hi = (_Float16)val;
        v = hl ? (_Float16)(val - (float)hi) : hi;
    }
    wf[i] = v;
}

// ---------------- K1: per-batch grid params — FROZEN (arcp f32, R11) -----
__global__ void k1_params(const float* __restrict__ pc, float* __restrict__ bparam) {
    __shared__ float r0[256], r1[256], r2[256], r3[256];
    __shared__ float sh[4];
    int b = blockIdx.x, t = threadIdx.x;
    const float* p = pc + (size_t)b*NN*3;
    float mnx=1e30f, mxx=-1e30f, mny=1e30f, mxy=-1e30f;
    for (int n=t; n<NN; n+=256) {
        float x=p[3*n], y=p[3*n+1];
        mnx=fminf(mnx,x); mxx=fmaxf(mxx,x); mny=fminf(mny,y); mxy=fmaxf(mxy,y);
    }
    r0[t]=mnx; r1[t]=mxx; r2[t]=mny; r3[t]=mxy;
    __syncthreads();
    for (int s=128; s>0; s>>=1) {
        if (t<s) { r0[t]=fminf(r0[t],r0[t+s]); r1[t]=fmaxf(r1[t],r1[t+s]);
                   r2[t]=fminf(r2[t],r2[t+s]); r3[t]=fmaxf(r3[t],r3[t+s]); }
        __syncthreads();
    }
    if (t==0) {
        float rx = __fsub_rn(r1[0], r0[0]);
        float ry = __fsub_rn(r3[0], r2[0]);
        sh[0]=r0[0]; sh[1]=r2[0];
        float c221 = __fdiv_rn(1.0f, (float)(OBJ-3));
        float grid = __fmul_rn(fmaxf(rx,ry), c221);
        sh[2] = grid;
        sh[3] = __fdiv_rn(1.0f, grid);               // hoisted reciprocal (arcp)
    }
    __syncthreads();
    float minx=sh[0], miny=sh[1], rgrid=sh[3];
    mnx=1e30f; mxx=-1e30f; mny=1e30f; mxy=-1e30f;
    for (int n=t; n<NN; n+=256) {
        float ix = floorf(__fmul_rn(__fsub_rn(p[3*n],   minx), rgrid));
        float iy = floorf(__fmul_rn(__fsub_rn(p[3*n+1], miny), rgrid));
        mnx=fminf(mnx,ix); mxx=fmaxf(mxx,ix); mny=fminf(mny,iy); mxy=fmaxf(mxy,iy);
    }
    __syncthreads();
    r0[t]=mnx; r1[t]=mxx; r2[t]=mny; r3[t]=mxy;
    __syncthreads();
    for (int s=128; s>0; s>>=1) {
        if (t<s) { r0[t]=fminf(r0[t],r0[t+s]); r1[t]=fmaxf(r1[t],r1[t+s]);
                   r2[t]=fminf(r2[t],r2[t+s]); r3[t]=fmaxf(r3[t],r3[t+s]); }
        __syncthreads();
    }
    if (t==0) {
        float cx = floorf((r1[0] + 2.0f + r0[0]) * 0.5f);
        float cy = floorf((r3[0] + 2.0f + r2[0]) * 0.5f);
        bparam[b*8+0]=minx; bparam[b*8+1]=miny; bparam[b*8+2]=sh[3];
        bparam[b*8+3]=112.0f - cx - 1.0f;
        bparam[b*8+4]=112.0f - cy - 1.0f;
    }
}

// ---------------- K2: linear grid indices — FROZEN (arcp) ----------------
__global__ void k2_lin(const float* __restrict__ pc, const float* __restrict__ bparam,
                       int* __restrict__ lin) {
    int i = blockIdx.x*256 + threadIdx.x;
    if (i >= BB*NN) return;
    int b = i / NN;
    float x = pc[(size_t)i*3], y = pc[(size_t)i*3+1];
    float minx=bparam[b*8], miny=bparam[b*8+1], rgrid=bparam[b*8+2];
    float offx=bparam[b*8+3], offy=bparam[b*8+4];
    float ix = floorf(__fmul_rn(__fsub_rn(x, minx), rgrid));
    float iy = floorf(__fmul_rn(__fsub_rn(y, miny), rgrid));
    const float o9x[9] = {-1,-1,-1, 0,0,0, 1,1,1};
    const float o9y[9] = {-1, 0, 1,-1,0,1,-1,0,1};
#pragma unroll
    for (int j=0; j<9; ++j) {
        float dx = ix + o9x[j] + 1.0f + offx;
        float dy = iy + o9y[j] + 1.0f + offy;
        dx += (dx < 0.f ? 1.f : 0.f) - (dx > 223.f ? 1.f : 0.f);
        dy += (dy < 0.f ? 1.f : 0.f) - (dy > 223.f ? 1.f : 0.f);
        lin[(size_t)i*9 + j] = (int)(dx*224.f + dy);
    }
}

// ---------------- K3: f0 = pc @ w_in^T + b_in ----------------
__global__ void k3_f0(const float* __restrict__ pc, const float* __restrict__ w_in,
                      const float* __restrict__ b_in, float* __restrict__ f0) {
    int i = blockIdx.x*256 + threadIdx.x;
    if (i >= BB*NN*8) return;
    int o = i & 7; int bn = i >> 3;
    float x=pc[(size_t)bn*3], y=pc[(size_t)bn*3+1], z=pc[(size_t)bn*3+2];
    f0[i] = x*w_in[o*3] + y*w_in[o*3+1] + z*w_in[o*3+2] + b_in[o];
}

// ---------------- K4: segmented KNN (R12 WIN config) ---------------------
__global__ __launch_bounds__(256) void k4_knn(const float* __restrict__ pc,
                                              float* __restrict__ pd,
                                              int* __restrict__ pi) {
    __shared__ float4 pts[SEGN];
    int b = blockIdx.y, t = threadIdx.x, seg = blockIdx.z;
    const float* p = pc + (size_t)b*NN*3;
    int m0 = seg*SEGN;
    for (int m=t; m<SEGN; m+=256) {
        int mm = m0 + m;
        float x=p[3*mm], y=p[3*mm+1], z=p[3*mm+2];
        float sq = __fadd_rn(__fadd_rn(__fmul_rn(x,x), __fmul_rn(y,y)), __fmul_rn(z,z));
        pts[m] = make_float4(x, y, z, sq);
    }
    __syncthreads();
    int n = blockIdx.x*256 + t;
    float mx = p[3*n], my = p[3*n+1], mz = p[3*n+2];
    float msq = __fadd_rn(__fadd_rn(__fmul_rn(mx,mx), __fmul_rn(my,my)), __fmul_rn(mz,mz));
    float bd[KNNK]; int bi[KNNK];
#pragma unroll
    for (int j=0; j<KNNK; ++j) { bd[j]=1e30f; bi[j]=0; }
#pragma unroll 8
    for (int m=0; m<SEGN; ++m) {
        float4 q = pts[m];
        float dot = __fadd_rn(__fadd_rn(__fmul_rn(mz,q.z), __fmul_rn(my,q.y)),
                              __fmul_rn(mx,q.x));
        float d = __fsub_rn(__fadd_rn(msq, q.w), __fmul_rn(2.0f, dot));
        if (d < bd[KNNK-1]) {
            float v=d; int vi=m0+m;
#pragma unroll
            for (int j=0; j<KNNK; ++j) {
                if (v < bd[j]) { float tv=bd[j]; int ti=bi[j]; bd[j]=v; bi[j]=vi; v=tv; vi=ti; }
            }
        }
    }
    size_t base = (((size_t)b*NN + n)*SEG + seg)*KNNK;
#pragma unroll
    for (int j=0; j<KNNK; ++j) { pd[base+j] = bd[j]; pi[base+j] = bi[j]; }
}

// ---------------- K4b: merge 4 sorted partial top-8 lists ----------------
__global__ void k4b_merge(const float* __restrict__ pd, const int* __restrict__ pi,
                          int* __restrict__ nidx) {
    int i = blockIdx.x*256 + threadIdx.x;
    if (i >= BB*NN) return;
    float d[SEG][KNNK]; int id[SEG][KNNK]; int ptr[SEG];
    size_t base = (size_t)i*SEG*KNNK;
#pragma unroll
    for (int s=0; s<SEG; ++s) {
        ptr[s]=0;
#pragma unroll
        for (int j=0; j<KNNK; ++j) { d[s][j]=pd[base+s*KNNK+j]; id[s][j]=pi[base+s*KNNK+j]; }
    }
#pragma unroll
    for (int j=0; j<KNNK; ++j) {
        int best=0; float bdv=1e30f; int bidx=0x7fffffff;
#pragma unroll
        for (int s=0; s<SEG; ++s) {
            float dv = (ptr[s]<KNNK) ? d[s][ptr[s]] : 1e30f;
            int   iv = (ptr[s]<KNNK) ? id[s][ptr[s]] : 0x7fffffff;
            if (dv < bdv || (dv == bdv && iv < bidx)) { best=s; bdv=dv; bidx=iv; }
        }
        nidx[(size_t)i*KNNK + j] = bidx;
        ptr[best]++;
    }
}

// ---------------- feat builder (shared by K5/K6) ----------------
__device__ __forceinline__ void build_feat(int t, int b, int n0,
        const float* __restrict__ f0, const int* __restrict__ nidx,
        float feat[4][8][16]) {
    int pt = t >> 6, k = (t >> 3) & 7, c = t & 7;
    int n  = n0 + pt;
    int nb = nidx[((size_t)b*NN + n)*8 + k];
    float f0c = f0[((size_t)b*NN + n)*8 + c];
    float fnc = f0[((size_t)b*NN + nb)*8 + c];
    feat[pt][k][c]   = fnc - f0c;
    feat[pt][k][c+8] = f0c;
}

// ---------------- K5: GroupNorm stats pass ----------------
__global__ __launch_bounds__(256) void k5_stats(const float* __restrict__ f0,
        const int* __restrict__ nidx, const float* __restrict__ w_graph,
        float* __restrict__ gsum) {
    __shared__ float wgT[16*64];
    __shared__ float feat[4][8][16];
    __shared__ float part[4][4][2];
    int t = threadIdx.x;
    for (int i=t; i<1024; i+=256) wgT[(i&15)*64 + (i>>4)] = w_graph[i];
    int blk = blockIdx.x;
    int b = blk >> 9, n0 = (blk & 511)*4;
    build_feat(t, b, n0, f0, nidx, feat);
    __syncthreads();
    int pt = t >> 6, o = t & 63;
    float s = 0.f, s2 = 0.f;
#pragma unroll
    for (int k=0; k<8; ++k) {
        float g = 0.f;
#pragma unroll
        for (int c=0; c<16; ++c) g = fmaf(feat[pt][k][c], wgT[c*64+o], g);
        s += g; s2 += g*g;
    }
#pragma unroll
    for (int off=8; off; off>>=1) {
        s  += __shfl_down(s,  off, 16);
        s2 += __shfl_down(s2, off, 16);
    }
    if ((o & 15) == 0) { part[pt][o>>4][0] = s; part[pt][o>>4][1] = s2; }
    __syncthreads();
    if (t < 8) {
        int grp = t >> 1, which = t & 1;
        float v = part[0][grp][which] + part[1][grp][which]
                + part[2][grp][which] + part[3][grp][which];
        atomicAdd(&gsum[(b*4+grp)*2 + which], v);
    }
}

__global__ void k5b_finalize(const float* __restrict__ gsum, float* __restrict__ gmu) {
    int t = threadIdx.x;
    if (t < 32) {
        const float cnt = (float)(NN*KNNK*16);
        float mu = gsum[t*2] / cnt;
        float var = gsum[t*2+1] / cnt - mu*mu;
        gmu[t*2]   = mu;
        gmu[t*2+1] = 1.0f / sqrtf(var + 1e-5f);
    }
}

// ---------------- K6: normalize + leaky + max_k + proj ----------------
__global__ __launch_bounds__(256) void k6_point(const float* __restrict__ f0,
        const int* __restrict__ nidx, const float* __restrict__ w_graph,
        const float* __restrict__ gmu, const float* __restrict__ gn_g,
        const float* __restrict__ gn_b, const float* __restrict__ w_proj,
        const float* __restrict__ b_proj, float* __restrict__ f) {
    __shared__ float wgT[16*64];
    __shared__ float wpT[64*64];
    __shared__ float feat[4][8][16];
    __shared__ float gmax_s[4][64];
    int t = threadIdx.x;
    for (int i=t; i<1024; i+=256) wgT[(i&15)*64 + (i>>4)] = w_graph[i];
    for (int i=t; i<4096; i+=256) wpT[(i&63)*64 + (i>>6)] = w_proj[i];
    int blk = blockIdx.x;
    int b = blk >> 9, n0 = (blk & 511)*4;
    build_feat(t, b, n0, f0, nidx, feat);
    __syncthreads();
    int pt = t >> 6, o = t & 63;
    int grp = o >> 4;
    float mu = gmu[(b*4+grp)*2], rsig = gmu[(b*4+grp)*2+1];
    float ga = gn_g[o], be = gn_b[o];
    float gm = -1e30f;
#pragma unroll
    for (int k=0; k<8; ++k) {
        float g = 0.f;
#pragma unroll
        for (int c=0; c<16; ++c) g = fmaf(feat[pt][k][c], wgT[c*64+o], g);
        float v = (g - mu)*rsig*ga + be;
        v = (v >= 0.f) ? v : 0.2f*v;
        gm = fmaxf(gm, v);
    }
    gmax_s[pt][o] = gm;
    __syncthreads();
    float acc = b_proj[o];
#pragma unroll
    for (int c=0; c<64; ++c) acc = fmaf(gmax_s[pt][c], wpT[c*64+o], acc);
    f[((size_t)b*NN + n0 + pt)*64 + o] = acc;
}

// ---------------- K7: scatter-sum onto NHWC grid (all batches) -----------
__global__ __launch_bounds__(256) void k7_scatter(const float* __restrict__ f,
        const int* __restrict__ lin, float* __restrict__ res) {
    int blk = blockIdx.x, t = threadIdx.x;
    int b = blk >> 9;
    int n = (blk & 511)*4 + (t >> 6);
    int o = t & 63;
    size_t bn = (size_t)b*NN + n;
    float v = f[bn*64 + o];
#pragma unroll
    for (int j=0; j<9; ++j) {
        int cell = lin[bn*9 + j];
        if (cell >= 0 && cell < HWD)
            atomicAdd(&res[((size_t)b*HWD + cell)*64 + o], v);
    }
}

// ======================= split-f16 MFMA conv engine =======================
// R2 -> R3: occupancy doubled but time flat -> latency-bound memory streams
// (FETCH+WRITE ~225MB @ measured 880 GB/s == whole dispatch time). The halo
// loads were under a divergent bounds branch -> one load in flight per iter.
// Now: clamped UNCONDITIONAL addresses, all 12 float4 loads issued
// back-to-back into regs (deep vmcnt pipeline), border zeroed by predicate
// afterwards. k9 additionally early-issues res-tile + wbk loads before the
// conv loop (T14 issue-early/consume-late).
// LDS map (bytes): haloH @0 [180][72]f16 (25920), haloL @25920,
//                  wlds @51840 (20480) -> 72320 total, 2 blocks/CU.
#define LDS2_BYTES 72320

__device__ __forceinline__ void conv_mfma_body(
        const float* __restrict__ sp, const _Float16* __restrict__ wf,
        _Float16* haloH, _Float16* haloL, _Float16* wlds,
        int x0, int y0, int t, int wid, int lr, int lg, f32x4v acc[2][4]) {
    // ---- halo stage: 10x18 cells x 64ch fp32 -> hi/lo f16 ----
    // batched: 12 unconditional clamped loads -> regs -> cvt+write
    float4 vreg[12];
#pragma unroll
    for (int j = 0; j < 12; ++j) {
        int i = j*256 + t; if (i > 2879) i = 2879;     // dup-load, harmless
        int cell = i >> 4, c4 = i & 15;
        int gy = y0 - 1 + cell/18, gx = x0 - 1 + cell%18;
        int cy = gy < 0 ? 0 : (gy > OBJ-1 ? OBJ-1 : gy);
        int cx = gx < 0 ? 0 : (gx > OBJ-1 ? OBJ-1 : gx);
        vreg[j] = *(const float4*)(sp + ((size_t)cy*OBJ + cx)*64 + c4*4);
    }
#pragma unroll
    for (int j = 0; j < 12; ++j) {
        int i = j*256 + t;
        if (i <= 2879) {
            int cell = i >> 4, c4 = i & 15;
            int gy = y0 - 1 + cell/18, gx = x0 - 1 + cell%18;
            bool inb = ((unsigned)gy < (unsigned)OBJ) && ((unsigned)gx < (unsigned)OBJ);
            float4 v = vreg[j];
            if (!inb) v = make_float4(0.f,0.f,0.f,0.f);
            _Float16 a0=(_Float16)v.x, a1=(_Float16)v.y, a2=(_Float16)v.z, a3=(_Float16)v.w;
            f16x4 hv = {a0, a1, a2, a3};
            f16x4 lv = {(_Float16)(v.x-(float)a0), (_Float16)(v.y-(float)a1),
                        (_Float16)(v.z-(float)a2), (_Float16)(v.w-(float)a3)};
            *(f16x4*)&haloH[cell*72 + c4*4] = hv;
            *(f16x4*)&haloL[cell*72 + c4*4] = lv;
        }
    }
    // ---- tap-0 weights: global -> regs -> LDS (1280 uint4 / 256 thr = 5) --
    uint4 wreg[5];
    {
        const uint4* s4 = (const uint4*)wf;
#pragma unroll
        for (int j=0; j<5; ++j) wreg[j] = s4[j*256 + t];
        uint4* d4 = (uint4*)wlds;
#pragma unroll
        for (int j=0; j<5; ++j) d4[j*256 + t] = wreg[j];
    }
    __syncthreads();
    // ---- K-loop: 9 taps x 2 kblocks, single weight buffer + async prefetch
    for (int tp = 0; tp < 9; ++tp) {
        if (tp < 8) {             // issue next tap's loads early (T14 split)
            const uint4* s4 = (const uint4*)(wf + (size_t)(tp+1)*10240);
#pragma unroll
            for (int j=0; j<5; ++j) wreg[j] = s4[j*256 + t];
        }
        int dy = tp/3, dx = tp - 3*(tp/3);
#pragma unroll
        for (int kb = 0; kb < 2; ++kb) {
            f16x8 ah[2], al[2], bh[4], bl[4];
#pragma unroll
            for (int m = 0; m < 2; ++m) {
                int off = ((2*wid + m + dy)*18 + lr + dx)*72 + kb*32 + lg*8;
                ah[m] = *(const f16x8*)&haloH[off];
                al[m] = *(const f16x8*)&haloL[off];
            }
#pragma unroll
            for (int n = 0; n < 4; ++n) {
                int off = (kb*128 + 16*n + lr)*40 + lg*8;   // hl=0 plane
                bh[n] = *(const f16x8*)&wlds[off];
                bl[n] = *(const f16x8*)&wlds[off + 2560];    // hl=1: +64*40
            }
#pragma unroll
            for (int m = 0; m < 2; ++m)
#pragma unroll
            for (int n = 0; n < 4; ++n) {
                acc[m][n] = __builtin_amdgcn_mfma_f32_16x16x32_f16(ah[m], bh[n], acc[m][n], 0,0,0);
                acc[m][n] = __builtin_amdgcn_mfma_f32_16x16x32_f16(al[m], bh[n], acc[m][n], 0,0,0);
                acc[m][n] = __builtin_amdgcn_mfma_f32_16x16x32_f16(ah[m], bl[n], acc[m][n], 0,0,0);
            }
        }
        __syncthreads();                      // all waves done reading wlds
        if (tp < 8) {
            uint4* d4 = (uint4*)wlds;
#pragma unroll
            for (int j=0; j<5; ++j) d4[j*256 + t] = wreg[j];
            __syncthreads();                  // tap tp+1 weights visible
        }
    }
}

// ---------------- K8: conv3x3 + scale/shift + relu (MFMA, 16x8 tile) -----
__global__ __launch_bounds__(256, 2) void k8m_conv1(
        const float* __restrict__ src, const _Float16* __restrict__ wf,
        const float* __restrict__ g1, const float* __restrict__ b1,
        float* __restrict__ dst) {
    __shared__ __align__(16) char smem[LDS2_BYTES];
    _Float16* haloH = (_Float16*)smem;
    _Float16* haloL = (_Float16*)(smem + 25920);
    _Float16* wlds  = (_Float16*)(smem + 51840);
    int x0 = blockIdx.x*16, y0 = blockIdx.y*8, b = blockIdx.z;
    int t = threadIdx.x, wid = t >> 6, lr = t & 15, lg = (t >> 4) & 3;
    f32x4v acc[2][4];
#pragma unroll
    for (int m=0;m<2;++m)
#pragma unroll
    for (int n=0;n<4;++n) acc[m][n] = (f32x4v){0.f,0.f,0.f,0.f};
    conv_mfma_body(src + (size_t)b*HWD*64, wf, haloH, haloL, wlds,
                   x0, y0, t, wid, lr, lg, acc);
    // ---- epilogue: scale/shift + relu, store NHWC ----
    float gv[4], bv[4];
#pragma unroll
    for (int n = 0; n < 4; ++n) { gv[n] = g1[16*n+lr]; bv[n] = b1[16*n+lr]; }
    float* dp = dst + (size_t)b*HWD*64;
#pragma unroll
    for (int m = 0; m < 2; ++m) {
        int py = 2*wid + m;
#pragma unroll
        for (int n = 0; n < 4; ++n)
#pragma unroll
        for (int r = 0; r < 4; ++r) {
            int px = lg*4 + r;
            dp[((size_t)(y0+py)*OBJ + (x0+px))*64 + 16*n + lr] =
                fmaxf(fmaf(acc[m][n][r], gv[n], bv[n]), 0.f);
        }
    }
}

// ---------------- K9: conv3x3 + bn + residual-relu + blkout + img head ---
__global__ __launch_bounds__(256, 2) void k9m_conv2(
        const float* __restrict__ h1, const _Float16* __restrict__ wf,
        const float* __restrict__ g2, const float* __restrict__ b2,
        const float* __restrict__ resi,
        const float* __restrict__ wbk, const float* __restrict__ bbk,
        const float* __restrict__ wim, const float* __restrict__ bim,
        float* __restrict__ outp) {
    __shared__ __align__(16) char smem[LDS2_BYTES];
    _Float16* haloH = (_Float16*)smem;
    _Float16* haloL = (_Float16*)(smem + 25920);
    _Float16* wlds  = (_Float16*)(smem + 51840);
    int x0 = blockIdx.x*16, y0 = blockIdx.y*8, b = blockIdx.z;
    int t = threadIdx.x, wid = t >> 6, lr = t & 15, lg = (t >> 4) & 3;
    // ---- early-issue (T14): res tile + wbk loads held in regs across conv
    float4 resreg[8], wbkreg[4];
    {
        const float* rp = resi + (size_t)b*HWD*64;
#pragma unroll
        for (int j=0; j<8; ++j) {
            int i = j*256 + t;
            int pix = i >> 4, c4 = i & 15;
            int gy = y0 + (pix >> 4), gx = x0 + (pix & 15);
            resreg[j] = *(const float4*)(rp + ((size_t)gy*OBJ + gx)*64 + c4*4);
        }
#pragma unroll
        for (int j=0; j<4; ++j) wbkreg[j] = ((const float4*)wbk)[j*256 + t];
    }
    f32x4v acc[2][4];
#pragma unroll
    for (int m=0;m<2;++m)
#pragma unroll
    for (int n=0;n<4;++n) acc[m][n] = (f32x4v){0.f,0.f,0.f,0.f};
    conv_mfma_body(h1 + (size_t)b*HWD*64, wf, haloH, haloL, wlds,
                   x0, y0, t, wid, lr, lg, acc);
    // conv loop ended with a barrier -> halo area & wlds reusable.
    // ---- phase A: reg-staged res tile -> LDS + wbk B-frags -> LDS ----
    float* reslds = (float*)smem;            // [128][68] f32 = 34816 B
#pragma unroll
    for (int j=0; j<8; ++j) {
        int i = j*256 + t;
        int pix = i >> 4, c4 = i & 15;
        *(float4*)&reslds[pix*68 + c4*4] = resreg[j];
    }
#pragma unroll
    for (int j=0; j<4; ++j) {
        int i4 = j*256 + t;
        int o = i4 >> 4, c4 = i4 & 15;
        float4 v = wbkreg[j];
#pragma unroll
        for (int e=0; e<4; ++e) {
            int c = c4*4 + e;
            float val = ((const float*)&v)[e];
            _Float16 hi = (_Float16)val;
            int kb2 = c >> 5, kk = c & 31;
            wlds[(kb2*128 + o)*40 + kk]      = hi;
            wlds[(kb2*128 + 64 + o)*40 + kk] = (_Float16)(val - (float)hi);
        }
    }
    float g2v[4], b2v[4];
#pragma unroll
    for (int n = 0; n < 4; ++n) { g2v[n] = g2[16*n+lr]; b2v[n] = b2[16*n+lr]; }
    __syncthreads();
    // ---- residual + relu into acc regs (reads reslds) ----
#pragma unroll
    for (int m = 0; m < 2; ++m)
#pragma unroll
    for (int n = 0; n < 4; ++n)
#pragma unroll
    for (int r = 0; r < 4; ++r) {
        int pix = 32*wid + 16*m + lg*4 + r;
        float tv = fmaf(acc[m][n][r], g2v[n], b2v[n]) + reslds[pix*68 + 16*n + lr];
        acc[m][n][r] = fmaxf(tv, 0.f);
    }
    __syncthreads();
    // ---- write t as hi/lo planes for blkout A-frags ----
    _Float16* thlH = (_Float16*)smem;                 // [128][72] f16 = 18432 B
    _Float16* thlL = (_Float16*)(smem + 18432);
#pragma unroll
    for (int m = 0; m < 2; ++m)
#pragma unroll
    for (int n = 0; n < 4; ++n)
#pragma unroll
    for (int r = 0; r < 4; ++r) {
        int pix = 32*wid + 16*m + lg*4 + r;
        float tv = acc[m][n][r];
        _Float16 hi = (_Float16)tv;
        thlH[pix*72 + 16*n + lr] = hi;
        thlL[pix*72 + 16*n + lr] = (_Float16)(tv - (float)hi);
    }
    __syncthreads();
    // ---- phase B: blkout GEMM (128x64, K=64) via split-f16 MFMA ----
    f32x4v a2[2][4];
#pragma unroll
    for (int m=0;m<2;++m)
#pragma unroll
    for (int n=0;n<4;++n) a2[m][n] = (f32x4v){0.f,0.f,0.f,0.f};
#pragma unroll
    for (int kb = 0; kb < 2; ++kb) {
        f16x8 ah[2], al[2], bh[4], bl[4];
#pragma unroll
        for (int m = 0; m < 2; ++m) {
            int off = (32*wid + 16*m + lr)*72 + kb*32 + lg*8;
            ah[m] = *(const f16x8*)&thlH[off];
            al[m] = *(const f16x8*)&thlL[off];
        }
#pragma unroll
        for (int n = 0; n < 4; ++n) {
            int off = (kb*128 + 16*n + lr)*40 + lg*8;
            bh[n] = *(const f16x8*)&wlds[off];
            bl[n] = *(const f16x8*)&wlds[off + 2560];
        }
#pragma unroll
        for (int m = 0; m < 2; ++m)
#pragma unroll
        for (int n = 0; n < 4; ++n) {
            a2[m][n] = __builtin_amdgcn_mfma_f32_16x16x32_f16(ah[m], bh[n], a2[m][n], 0,0,0);
            a2[m][n] = __builtin_amdgcn_mfma_f32_16x16x32_f16(al[m], bh[n], a2[m][n], 0,0,0);
            a2[m][n] = __builtin_amdgcn_mfma_f32_16x16x32_f16(ah[m], bl[n], a2[m][n], 0,0,0);
        }
    }
    __syncthreads();          // all thl reads done before ureg overwrites
    // ---- write u = blkout + bbk into LDS [128][68] f32 ----
    float* ureg = (float*)smem;
    float bkv[4];
#pragma unroll
    for (int n = 0; n < 4; ++n) bkv[n] = bbk[16*n+lr];
#pragma unroll
    for (int m = 0; m < 2; ++m)
#pragma unroll
    for (int n = 0; n < 4; ++n)
#pragma unroll
    for (int r = 0; r < 4; ++r) {
        int pix = 32*wid + 16*m + lg*4 + r;
        ureg[pix*68 + 16*n + lr] = a2[m][n][r] + bkv[n];
    }
    __syncthreads();
    // ---- phase C: img head (3 outputs, VALU) + sigmoid + normalize ----
    if (t < 128) {
        const float MEAN[3] = {0.485f, 0.456f, 0.406f};
        const float STDV[3] = {0.229f, 0.224f, 0.225f};
        int pix = t, py = pix >> 4, px = pix & 15;
#pragma unroll
        for (int o3 = 0; o3 < 3; ++o3) {
            float s = bim[o3];
            for (int c = 0; c < 64; ++c)
                s = fmaf(wim[o3*64 + c], ureg[pix*68 + c], s);
            float sig = 1.f/(1.f + expf(-s));
            outp[((size_t)(b*3 + o3))*HWD + (size_t)(y0+py)*OBJ + (x0+px)] =
                (sig - MEAN[o3]) / STDV[o3];
        }
    }
}

// ---------------- launch ----------------
extern "C" void kernel_launch(void* const* d_in, const int* in_sizes, int n_in,
                              void* d_out, int out_size, void* d_ws, size_t ws_size,
                              hipStream_t stream) {
    const float* pc      = (const float*)d_in[0];
    const float* w_in    = (const float*)d_in[1];
    const float* b_in    = (const float*)d_in[2];
    const float* w_graph = (const float*)d_in[3];
    const float* gn_g    = (const float*)d_in[4];
    const float* gn_b    = (const float*)d_in[5];
    const float* w_proj  = (const float*)d_in[6];
    const float* b_proj  = (const float*)d_in[7];
    const float* bb_w1   = (const float*)d_in[8];
    const float* bb_g1   = (const float*)d_in[9];
    const float* bb_b1   = (const float*)d_in[10];
    const float* bb_w2   = (const float*)d_in[11];
    const float* bb_g2   = (const float*)d_in[12];
    const float* bb_b2   = (const float*)d_in[13];
    const float* w_blkout= (const float*)d_in[14];
    const float* b_blkout= (const float*)d_in[15];
    const float* w_img   = (const float*)d_in[16];
    const float* b_img   = (const float*)d_in[17];

    float* ws     = (float*)d_ws;
    float* res    = ws + RES_OFF;
    float* h1     = ws + H1_OFF;
    float* pd     = ws + H1_OFF;
    int*   pi     = (int*)(ws + H1_OFF + (size_t)BB*NN*SEG*KNNK);
    float* f      = ws + F_OFF;
    float* f0     = ws + F0_OFF;
    float* bparam = ws + BP_OFF;
    float* gsum   = ws + GS_OFF;
    float* gmu    = ws + GM_OFF;
    _Float16* wt1f = (_Float16*)(ws + WT1_OFF);
    _Float16* wt2f = (_Float16*)(ws + WT2_OFF);
    int*   lin    = (int*)(ws + INT_OFF);
    int*   nidx   = lin + (size_t)BB*NN*9;
    float* out    = (float*)d_out;

    hipMemsetAsync(res, 0, RES_SZ*sizeof(float), stream);
    hipMemsetAsync(gsum, 0, 64*sizeof(float), stream);

    k0_wtf<<<360, 256, 0, stream>>>(bb_w1, wt1f);
    k0_wtf<<<360, 256, 0, stream>>>(bb_w2, wt2f);
    k1_params<<<BB, 256, 0, stream>>>(pc, bparam);
    k2_lin<<<(BB*NN)/256, 256, 0, stream>>>(pc, bparam, lin);
    k3_f0<<<(BB*NN*8)/256, 256, 0, stream>>>(pc, w_in, b_in, f0);
    k4_knn<<<dim3(NN/256, BB, SEG), 256, 0, stream>>>(pc, pd, pi);
    k4b_merge<<<(BB*NN)/256, 256, 0, stream>>>(pd, pi, nidx);
    k5_stats<<<(BB*NN)/4, 256, 0, stream>>>(f0, nidx, w_graph, gsum);
    k5b_finalize<<<1, 64, 0, stream>>>(gsum, gmu);
    k6_point<<<(BB*NN)/4, 256, 0, stream>>>(f0, nidx, w_graph, gmu, gn_g, gn_b,
                                            w_proj, b_proj, f);
    k7_scatter<<<(BB*NN)/4, 256, 0, stream>>>(f, lin, res);
    k8m_conv1<<<dim3(14, 28, BB), 256, 0, stream>>>(res, wt1f, bb_g1, bb_b1, h1);
    k9m_conv2<<<dim3(14, 28, BB), 256, 0, stream>>>(h1, wt2f, bb_g2, bb_b2, res,
                                                    w_blkout, b_blkout, w_img, b_img, out);
}